// Round 12
// baseline (1920.945 us; speedup 1.0000x reference)
//
#include <hip/hip_runtime.h>
#include <math.h>

#define B 8
#define D 1024
#define T 4096
#define Q 8
#define K 1024
#define CD 32
#define BT (B * T)

// ---------------- scratch layout inside d_out (bytes) ----------------
// d_out floats [0 .. B*D*T) are scratch until k_gemm_final (last kernel) writes them.
// k_gemm_final reads ONLY inputs + idxi (in d_ws) -> no overlap hazard.
#define OFF_Z0   ((size_t)0)                            // f64 [Q][B][CD][T]  64 MB
#define OFF_MT   (OFF_Z0 + (size_t)Q * B * CD * T * 8)  // f64 [8][8][K][CD]  16 MB
#define OFF_CBN  (OFF_MT + (size_t)64 * K * CD * 8)     // f64 [Q][K][CD]      2 MB
#define OFF_N264 (OFF_CBN + (size_t)Q * K * CD * 8)     // f64 [Q][K]         64 KB
#define OFF_NT   (OFF_N264 + (size_t)Q * K * 8)         // f64 [64][CD][CD]  512 KB
#define OFF_BEFF (OFF_NT + (size_t)64 * CD * CD * 8)    // f64 [Q][CD]         2 KB
#define OFF_C32  (OFF_BEFF + (size_t)Q * CD * 8)        // f32 [Q][K][CD]      1 MB
#define OFF_N232 (OFF_C32 + (size_t)Q * K * CD * 4)     // f32 [Q][K]         32 KB
#define OFF_W64  (OFF_N232 + (size_t)Q * K * 4)         // f64 [Q][CD][D]      2 MB
// idxi i32 [Q][BT] lives in d_ws @ 0 (1 MB)

__global__ void k_zero_losses(float* __restrict__ loss) {
    if (threadIdx.x < Q) loss[threadIdx.x] = 0.0f;
}

// Normalize codebooks fp64 + fp32 copies for the prefilter.
__global__ __launch_bounds__(256) void k_norm(const float* __restrict__ cb,
                                              double* __restrict__ cbn64,
                                              double* __restrict__ n264,
                                              float* __restrict__ cbn32,
                                              float* __restrict__ n232) {
    int i = blockIdx.x * 256 + threadIdx.x;   // 0..Q*K-1
    const float* c = cb + (size_t)i * CD;
    double v[CD];
    double ss = 0.0;
#pragma unroll
    for (int j = 0; j < CD; ++j) { v[j] = (double)c[j]; ss += v[j] * v[j]; }
    double s = 1.0 / sqrt(ss + 1e-12);
    double n2 = 0.0;
    double* o = cbn64 + (size_t)i * CD;
    float* o32 = cbn32 + (size_t)i * CD;
#pragma unroll
    for (int j = 0; j < CD; ++j) {
        double vn = v[j] * s;
        o[j] = vn; o32[j] = (float)vn; n2 += vn * vn;
    }
    n264[i] = n2; n232[i] = (float)n2;
}

// Win -> fp64 copy
__global__ __launch_bounds__(256) void k_cvtW(const float* __restrict__ Win,
                                              double* __restrict__ Win64) {
    int i = blockIdx.x * 256 + threadIdx.x;
    Win64[i] = (double)Win[i];
}

// N[q][j][c][c'] = sum_d Win_q[c,d] * Wout_j[d,c']   (fp64)
__global__ __launch_bounds__(256) void k_prep_N(const float* __restrict__ Win,
                                                const float* __restrict__ Wout,
                                                double* __restrict__ Ntab) {
    const int q = blockIdx.x >> 3, j = blockIdx.x & 7;
    __shared__ float a_sh[CD][128];
    __shared__ float b_sh[128][CD];
    double acc[4] = {0.0, 0.0, 0.0, 0.0};
    for (int d0 = 0; d0 < D; d0 += 128) {
        __syncthreads();
        for (int i = threadIdx.x; i < CD * 128; i += 256) {
            int cc = i >> 7, dl = i & 127;
            a_sh[cc][dl] = Win[((size_t)q * CD + cc) * D + d0 + dl];
        }
        for (int i = threadIdx.x; i < 128 * CD; i += 256) {
            int dl = i >> 5, cc = i & 31;
            b_sh[dl][cc] = Wout[((size_t)j * D + d0 + dl) * CD + cc];
        }
        __syncthreads();
        for (int dl = 0; dl < 128; ++dl) {
#pragma unroll
            for (int r = 0; r < 4; ++r) {
                int i = r * 256 + threadIdx.x;
                acc[r] = fma((double)a_sh[i >> 5][dl], (double)b_sh[dl][i & 31], acc[r]);
            }
        }
    }
#pragma unroll
    for (int r = 0; r < 4; ++r) {
        int i = r * 256 + threadIdx.x;
        Ntab[((size_t)(q * 8 + j) * CD + (i >> 5)) * CD + (i & 31)] = acc[r];
    }
}

// M[q][j][k][c] = sum_c' N[q][j][c][c'] * cb_j[k][c']   (fp64)
__global__ __launch_bounds__(256) void k_prep_M(const float* __restrict__ cb,
                                                const double* __restrict__ Ntab,
                                                double* __restrict__ Mt) {
    const int q = blockIdx.z, j = blockIdx.y;
    const int k = blockIdx.x * 256 + threadIdx.x;
    __shared__ double nsh[CD][CD];
    for (int i = threadIdx.x; i < CD * CD; i += 256)
        nsh[i >> 5][i & 31] = Ntab[(size_t)(q * 8 + j) * CD * CD + i];
    __syncthreads();
    double cv[CD];
    const float* cr = cb + ((size_t)j * K + k) * CD;
#pragma unroll
    for (int c = 0; c < CD; ++c) cv[c] = (double)cr[c];
    double* mo = Mt + (((size_t)(q * 8 + j) * K + k) * CD);
#pragma unroll
    for (int c = 0; c < CD; ++c) {
        double a = 0.0;
#pragma unroll
        for (int cp = 0; cp < CD; ++cp) a = fma(nsh[c][cp], cv[cp], a);
        mo[c] = a;
    }
}

// beff[q][c] = b_in[q][c] - sum_d Win_q[c][d] * (sum_{j<q} b_out[j][d])
__global__ __launch_bounds__(256) void k_prep_beff(const float* __restrict__ Win,
                                                   const float* __restrict__ b_in,
                                                   const float* __restrict__ b_out,
                                                   double* __restrict__ beff) {
    const int c = blockIdx.x, q = blockIdx.y;
    __shared__ double red[256];
    double p = 0.0;
    for (int d = threadIdx.x; d < D; d += 256) {
        double bp = 0.0;
        for (int j = 0; j < q; ++j) bp += (double)b_out[j * D + d];
        p = fma((double)Win[((size_t)q * CD + c) * D + d], bp, p);
    }
    red[threadIdx.x] = p;
    __syncthreads();
    for (int s = 128; s > 0; s >>= 1) {
        if (threadIdx.x < s) red[threadIdx.x] += red[threadIdx.x + s];
        __syncthreads();
    }
    if (threadIdx.x == 0) beff[q * CD + c] = (double)b_in[q * CD + c] - red[0];
}

// z0[q][b][c][t] = beff[q][c] + sum_d Win_q[c][d] * x[b][d][t]  (fp64)
// 2 t per thread (t, t+256): halves the uniform weight s_load stream, doubles
// FMA ILP. Per-(c,t) chain order identical to rounds 3-11 -> z0 bit-identical.
__global__ __launch_bounds__(256, 4) void k_gemmZ(const float* __restrict__ x,
                                                  const double* __restrict__ Win64,
                                                  const double* __restrict__ beff,
                                                  double* __restrict__ z0) {
    int h = blockIdx.x;                 // 0..511
    int u = h >> 3, r = h & 7;
    int q = u & 7;
    int m = r + 8 * (u >> 3);           // 0..63
    int b = m >> 3;
    int tc = m & 7;
    int t = tc * 512 + threadIdx.x;     // t and t+256
    const int c0 = blockIdx.y * (CD / 2);

    const double* w = Win64 + ((size_t)q * CD + c0) * D;
    const double* be = beff + q * CD + c0;
    const float* xp = x + (size_t)b * D * T + t;

    double acca[CD / 2], accb[CD / 2];
#pragma unroll
    for (int c = 0; c < CD / 2; ++c) { acca[c] = be[c]; accb[c] = be[c]; }

    for (int d0 = 0; d0 < D; d0 += 8) {
        double xa[8], xb8[8];
#pragma unroll
        for (int i = 0; i < 8; ++i) {
            xa[i] = (double)xp[(size_t)(d0 + i) * T];
            xb8[i] = (double)xp[(size_t)(d0 + i) * T + 256];
        }
#pragma unroll
        for (int c = 0; c < CD / 2; ++c) {
            const double* wc = w + (size_t)c * D + d0;
#pragma unroll
            for (int i = 0; i < 8; ++i) {
                acca[c] = fma(wc[i], xa[i], acca[c]);
                accb[c] = fma(wc[i], xb8[i], accb[c]);
            }
        }
    }
    double* zo = z0 + (((size_t)q * B + b) * CD + c0) * T + t;
#pragma unroll
    for (int c = 0; c < CD / 2; ++c) {
        zo[(size_t)c * T] = acca[c];
        zo[(size_t)c * T + 256] = accb[c];
    }
}

// insert (dd,ii) into sorted top-4 (d1<=d2<=d3<=d4)
#define INS4(dd, ii)                                                           \
    do {                                                                       \
        float _d = (dd); int _i = (ii);                                        \
        if (_d < d4) {                                                         \
            d4 = _d; i4 = _i;                                                  \
            if (d4 < d3) { float tf = d3; d3 = d4; d4 = tf; int ti = i3; i3 = i4; i4 = ti; } \
            if (d3 < d2) { float tf = d2; d2 = d3; d3 = tf; int ti = i2; i2 = i3; i3 = ti; } \
            if (d2 < d1) { float tf = d1; d1 = d2; d2 = tf; int ti = i1; i1 = i2; i2 = ti; } \
        }                                                                      \
    } while (0)

// ---------- fused 8-stage argmin, 8-wave blocks (round-10 proven version) ----------
#define AT 64
#define NW 8
#define KPW (K / NW)
__global__ __launch_bounds__(512) void k_argmin_fused(const double* __restrict__ z0,
                                                      const double* __restrict__ Mt,
                                                      const double* __restrict__ cbn64,
                                                      const double* __restrict__ n264,
                                                      const float* __restrict__ cbn32,
                                                      const float* __restrict__ n232,
                                                      const float* __restrict__ cb,
                                                      int* __restrict__ idxi,
                                                      float* __restrict__ idx_f,
                                                      float* __restrict__ loss) {
    const int lane = threadIdx.x & 63;
    const int wv = threadIdx.x >> 6;                        // 0..7
    const int kcw = __builtin_amdgcn_readfirstlane(wv);     // uniform wave id
    const int t = blockIdx.x * AT + lane;
    const int b = blockIdx.y;
    const size_t bt = (size_t)b * T + t;

    __shared__ double zn_s[CD][AT];       // 16 KB (RAW z, fp64)
    __shared__ float  sd[NW][4][AT];      //  8 KB
    __shared__ int    si[NW][4][AT];      //  8 KB
    __shared__ double ed[4][AT];          //  2 KB (candidate fp64 dists)
    __shared__ int    hist_s[Q][AT];      //  2 KB

    for (int q = 0; q < Q; ++q) {
        // ---- Phase A: distributed reconstruct (exact j-ascending chain per channel) ----
        {
            const int c0 = wv * 4;
            const double* zb = z0 + (((size_t)q * B + b) * CD + c0) * T + t;
            double v0 = zb[0];
            double v1 = zb[(size_t)T];
            double v2 = zb[(size_t)2 * T];
            double v3 = zb[(size_t)3 * T];
            for (int j = 0; j < q; ++j) {
                int kj = hist_s[j][lane];
                const double* m = Mt + (((size_t)(q * 8 + j) * K + kj) * CD) + c0;
                v0 -= m[0];
                v1 -= m[1];
                v2 -= m[2];
                v3 -= m[3];
            }
            zn_s[c0][lane] = v0;
            zn_s[c0 + 1][lane] = v1;
            zn_s[c0 + 2][lane] = v2;
            zn_s[c0 + 3][lane] = v3;
        }
        __syncthreads();

        // ---- Phase C: per-wave local normalize (bit-identical) + fp32 top-4 scan ----
        double s, rnorm;
        float d1 = 1e30f, d2 = 1e30f, d3 = 1e30f, d4 = 1e30f;
        int i1 = 0, i2 = 0, i3 = 0, i4 = 0;
        {
            double ss = 0.0;
#pragma unroll
            for (int c = 0; c < CD; ++c) { double v = zn_s[c][lane]; ss += v * v; }
            rnorm = sqrt(ss + 1e-12);
            s = 1.0 / rnorm;
            float znf[CD];
            float a2 = 0.0f;
#pragma unroll
            for (int c = 0; c < CD; ++c) {
                double vn = zn_s[c][lane] * s;
                float zf = (float)vn;
                znf[c] = zf;
                a2 = fmaf(zf, zf, a2);
            }

            const float4* cp = (const float4*)(cbn32 + ((size_t)q * K + (size_t)kcw * KPW) * CD);
            const float* nq = n232 + q * K + kcw * KPW;
            for (int k = 0; k < KPW; k += 4) {
                const float4* c0 = cp + k * (CD / 4);
                float p0 = 0.f, p1 = 0.f, p2 = 0.f, p3 = 0.f;
                float r0 = 0.f, r1 = 0.f, r2 = 0.f, r3 = 0.f;
                float s0 = 0.f, s1 = 0.f, s2 = 0.f, s3 = 0.f;
                float u0 = 0.f, u1 = 0.f, u2 = 0.f, u3 = 0.f;
#pragma unroll
                for (int u = 0; u < CD / 4; ++u) {
                    float4 av = c0[u];
                    float4 bv = c0[u + 8];
                    float4 cv = c0[u + 16];
                    float4 dv = c0[u + 24];
                    float z0f = znf[u * 4 + 0], z1f = znf[u * 4 + 1];
                    float z2f = znf[u * 4 + 2], z3f = znf[u * 4 + 3];
                    p0 = fmaf(z0f, av.x, p0); p1 = fmaf(z1f, av.y, p1);
                    p2 = fmaf(z2f, av.z, p2); p3 = fmaf(z3f, av.w, p3);
                    r0 = fmaf(z0f, bv.x, r0); r1 = fmaf(z1f, bv.y, r1);
                    r2 = fmaf(z2f, bv.z, r2); r3 = fmaf(z3f, bv.w, r3);
                    s0 = fmaf(z0f, cv.x, s0); s1 = fmaf(z1f, cv.y, s1);
                    s2 = fmaf(z2f, cv.z, s2); s3 = fmaf(z3f, cv.w, s3);
                    u0 = fmaf(z0f, dv.x, u0); u1 = fmaf(z1f, dv.y, u1);
                    u2 = fmaf(z2f, dv.z, u2); u3 = fmaf(z3f, dv.w, u3);
                }
                float dist0 = fmaf(-2.0f, (p0 + p1) + (p2 + p3), a2) + nq[k];
                float dist1 = fmaf(-2.0f, (r0 + r1) + (r2 + r3), a2) + nq[k + 1];
                float dist2 = fmaf(-2.0f, (s0 + s1) + (s2 + s3), a2) + nq[k + 2];
                float dist3 = fmaf(-2.0f, (u0 + u1) + (u2 + u3), a2) + nq[k + 3];
                INS4(dist0, kcw * KPW + k);
                INS4(dist1, kcw * KPW + k + 1);
                INS4(dist2, kcw * KPW + k + 2);
                INS4(dist3, kcw * KPW + k + 3);
            }
            sd[wv][0][lane] = d1; sd[wv][1][lane] = d2;
            sd[wv][2][lane] = d3; sd[wv][3][lane] = d4;
            si[wv][0][lane] = i1; si[wv][1][lane] = i2;
            si[wv][2][lane] = i3; si[wv][3][lane] = i4;
        }
        __syncthreads();

        // ---- Phase C2: waves 0-3 full merge + conditional distributed fp64 eval ----
        if (wv < 4) {
            d1 = d2 = d3 = d4 = 1e30f; i1 = i2 = i3 = i4 = 0;
            for (int w = 0; w < NW; ++w)
#pragma unroll
                for (int s4 = 0; s4 < 4; ++s4)
                    INS4(sd[w][s4][lane], si[w][s4][lane]);

            // eval needed only in the band gap2 < 1e-4 <= gap4
            if (d2 - d1 < 1e-4f && d4 - d1 >= 1e-4f) {
                int j1 = i1, j2 = i2, j3 = i3, j4 = i4;
                { int tt; if (j1 > j2) { tt = j1; j1 = j2; j2 = tt; }
                          if (j3 > j4) { tt = j3; j3 = j4; j4 = tt; }
                          if (j1 > j3) { tt = j1; j1 = j3; j3 = tt; }
                          if (j2 > j4) { tt = j2; j2 = j4; j4 = tt; }
                          if (j2 > j3) { tt = j2; j2 = j3; j3 = tt; } }
                const int myj = (wv == 0) ? j1 : (wv == 1) ? j2 : (wv == 2) ? j3 : j4;
                const double* cp64 = cbn64 + ((size_t)q * K + myj) * CD;
                double A = 0.0, dot = 0.0;
#pragma unroll
                for (int c = 0; c < CD; ++c) {
                    double vn = zn_s[c][lane] * s;    // identical bits to round-5 zn
                    A += vn * vn;
                    dot = fma(vn, cp64[c], dot);
                }
                ed[wv][lane] = (A - 2.0 * dot) + n264[(size_t)q * K + myj];
            }
        }
        __syncthreads();

        // ---- Phase D: wave 0 final pick + loss + writes ----
        if (wv == 0) {
            int bi;
            if (d2 - d1 >= 1e-4f) {
                bi = i1;                      // provably the fp64 argmin
            } else if (d4 - d1 >= 1e-4f) {
                int j1 = i1, j2 = i2, j3 = i3, j4 = i4;
                { int tt; if (j1 > j2) { tt = j1; j1 = j2; j2 = tt; }
                          if (j3 > j4) { tt = j3; j3 = j4; j4 = tt; }
                          if (j1 > j3) { tt = j1; j1 = j3; j3 = tt; }
                          if (j2 > j4) { tt = j2; j2 = j4; j4 = tt; }
                          if (j2 > j3) { tt = j2; j2 = j3; j3 = tt; } }
                double e1 = ed[0][lane], e2 = ed[1][lane];
                double e3 = ed[2][lane], e4 = ed[3][lane];
                double best = e1; bi = j1;
                if (e2 < best) { best = e2; bi = j2; }
                if (e3 < best) { best = e3; bi = j3; }
                if (e4 < best) { best = e4; bi = j4; }
            } else {
                // rare full fp64 rescan (exact round-1 formula; 2-code ILP)
                double zn[CD]; double A = 0.0;
#pragma unroll
                for (int c = 0; c < CD; ++c) {
                    zn[c] = zn_s[c][lane] * s;
                    A += zn[c] * zn[c];
                }
                double best = 1e300; bi = 0;
                const double* cq64 = cbn64 + (size_t)q * K * CD;
                const double* nq64 = n264 + (size_t)q * K;
                for (int k = 0; k < K; k += 2) {
                    double dot0 = 0.0, dot1 = 0.0;
                    const double* c0 = cq64 + (size_t)k * CD;
                    const double* c1 = c0 + CD;
#pragma unroll
                    for (int c = 0; c < CD; ++c) {
                        dot0 = fma(zn[c], c0[c], dot0);
                        dot1 = fma(zn[c], c1[c], dot1);
                    }
                    double dist0 = (A - 2.0 * dot0) + nq64[k];
                    double dist1 = (A - 2.0 * dot1) + nq64[k + 1];
                    if (dist0 < best) { best = dist0; bi = k; }
                    if (dist1 < best) { best = dist1; bi = k + 1; }
                }
            }
            hist_s[q][lane] = bi;

            const float* cr = cb + ((size_t)q * K + bi) * CD;
            double sq = 0.0;
#pragma unroll
            for (int c = 0; c < CD; ++c) {
                double vn = zn_s[c][lane] * s;                    // = round-5 zn bits
                double diff = vn * rnorm - (double)cr[c];         // round-1 loss form
                sq = fma(diff, diff, sq);
            }
#pragma unroll
            for (int off = 32; off > 0; off >>= 1) sq += __shfl_down(sq, off);
            if (lane == 0)
                atomicAdd(&loss[q], (float)(sq * (1.25 / (double)((size_t)B * CD * T))));
            idxi[q * BT + bt] = bi;
            idx_f[(size_t)q * BT + bt] = (float)bi;
        }
        __syncthreads();   // WAR: zn_s/sd/si/ed reused; hist_s visible to Phase A
    }
}

// ---------- k_final as register-blocked fp32 GEMM, T14 stage-split ----------
// Staging loads (Wout rows + idx-gathered cb rows) are issued into registers
// BEFORE the WAR barrier so their latency hides under the previous j's FMA
// burst; LDS stores happen after. Values and compute order unchanged.
#define GT 128
#define GD 128
__global__ __launch_bounds__(256) void k_gemm_final(const float* __restrict__ Wout,
                                                    const float* __restrict__ bo,
                                                    const float* __restrict__ cb,
                                                    const int* __restrict__ idxi,
                                                    float* __restrict__ out) {
    const int t0 = blockIdx.x * GT;
    const int b  = blockIdx.y;
    const int d0 = blockIdx.z * GD;
    const int tx = threadIdx.x & 15;
    const int ty = threadIdx.x >> 4;
    __shared__ float Wt[CD][GD + 4];
    __shared__ float Zt[CD][GT + 4];
    __shared__ float bsum[GD];

    if (threadIdx.x < GD) {
        float sjb = 0.0f;
#pragma unroll
        for (int j = 0; j < Q; ++j) sjb += bo[j * D + d0 + threadIdx.x];
        bsum[threadIdx.x] = sjb;
    }

    float acc[8][8];
#pragma unroll
    for (int r = 0; r < 8; ++r)
#pragma unroll
        for (int cc = 0; cc < 8; ++cc) acc[r][cc] = 0.0f;

    for (int j = 0; j < Q; ++j) {
        // prefetch staging data into registers (no LDS touch -> safe pre-barrier)
        float4 wv[4], zv[4];
#pragma unroll
        for (int r = 0; r < 4; ++r) {
            int i4 = threadIdx.x + r * 256;            // float4 idx, 0..1023
            wv[r] = ((const float4*)(Wout + ((size_t)j * D + d0) * CD))[i4];
            int rowi = i4 >> 3;                        // 0..127
            int kj = idxi[j * BT + (size_t)b * T + t0 + rowi];
            zv[r] = ((const float4*)(cb + ((size_t)j * K + kj) * CD))[i4 & 7];
        }
        __syncthreads();   // WAR: previous iter's reads of Wt/Zt done
#pragma unroll
        for (int r = 0; r < 4; ++r) {
            int i4 = threadIdx.x + r * 256;
            int rowi = i4 >> 3;
            int cq = (i4 & 7) * 4;
            Wt[cq][rowi] = wv[r].x; Wt[cq + 1][rowi] = wv[r].y;
            Wt[cq + 2][rowi] = wv[r].z; Wt[cq + 3][rowi] = wv[r].w;
            Zt[cq][rowi] = zv[r].x; Zt[cq + 1][rowi] = zv[r].y;
            Zt[cq + 2][rowi] = zv[r].z; Zt[cq + 3][rowi] = zv[r].w;
        }
        __syncthreads();
#pragma unroll
        for (int k = 0; k < CD; ++k) {
            float a[8], zb[8];
            *(float4*)&a[0]  = *(const float4*)&Wt[k][ty * 8];
            *(float4*)&a[4]  = *(const float4*)&Wt[k][ty * 8 + 4];
            *(float4*)&zb[0] = *(const float4*)&Zt[k][tx * 8];
            *(float4*)&zb[4] = *(const float4*)&Zt[k][tx * 8 + 4];
#pragma unroll
            for (int r = 0; r < 8; ++r)
#pragma unroll
                for (int cc = 0; cc < 8; ++cc)
                    acc[r][cc] = fmaf(a[r], zb[cc], acc[r][cc]);
        }
    }
#pragma unroll
    for (int r = 0; r < 8; ++r) {
        const int d = d0 + ty * 8 + r;
        const float bias = bsum[ty * 8 + r];
        float4 v0, v1;
        v0.x = acc[r][0] + bias; v0.y = acc[r][1] + bias;
        v0.z = acc[r][2] + bias; v0.w = acc[r][3] + bias;
        v1.x = acc[r][4] + bias; v1.y = acc[r][5] + bias;
        v1.z = acc[r][6] + bias; v1.w = acc[r][7] + bias;
        float* op = out + ((size_t)b * D + d) * T + t0 + tx * 8;
        *(float4*)op = v0;
        *(float4*)(op + 4) = v1;
    }
}

extern "C" void kernel_launch(void* const* d_in, const int* in_sizes, int n_in,
                              void* d_out, int out_size, void* d_ws, size_t ws_size,
                              hipStream_t stream) {
    const float* x     = (const float*)d_in[0];
    const float* Win   = (const float*)d_in[1];
    const float* b_in  = (const float*)d_in[2];
    const float* Wout  = (const float*)d_in[3];
    const float* b_out = (const float*)d_in[4];
    const float* cb    = (const float*)d_in[5];

    float* out0  = (float*)d_out;
    float* idx_f = out0 + (size_t)B * D * T;
    float* loss  = idx_f + (size_t)Q * BT;

    char* sc = (char*)d_out;   // scratch: dead before k_gemm_final writes out0
    double* z0    = (double*)(sc + OFF_Z0);
    double* Mt    = (double*)(sc + OFF_MT);
    double* cbn64 = (double*)(sc + OFF_CBN);
    double* n264  = (double*)(sc + OFF_N264);
    double* Ntab  = (double*)(sc + OFF_NT);
    double* beff  = (double*)(sc + OFF_BEFF);
    float*  cbn32 = (float*)(sc + OFF_C32);
    float*  n232  = (float*)(sc + OFF_N232);
    double* Win64 = (double*)(sc + OFF_W64);
    int*    idxi  = (int*)d_ws;                  // 1 MB, safe for gemm_final

    k_zero_losses<<<1, 64, 0, stream>>>(loss);
    k_norm<<<(Q * K) / 256, 256, 0, stream>>>(cb, cbn64, n264, cbn32, n232);
    k_cvtW<<<(Q * CD * D) / 256, 256, 0, stream>>>(Win, Win64);
    k_prep_N<<<64, 256, 0, stream>>>(Win, Wout, Ntab);
    k_prep_M<<<dim3(K / 256, 8, 8), 256, 0, stream>>>(cb, Ntab, Mt);
    k_prep_beff<<<dim3(CD, Q), 256, 0, stream>>>(Win, b_in, b_out, beff);

    k_gemmZ<<<dim3(Q * B * (T / 512), 2), 256, 0, stream>>>(x, Win64, beff, z0);

    k_argmin_fused<<<dim3(T / AT, B), 512, 0, stream>>>(z0, Mt, cbn64, n264,
                                                        cbn32, n232, cb,
                                                        idxi, idx_f, loss);

    k_gemm_final<<<dim3(T / GT, B, D / GD), 256, 0, stream>>>(Wout, b_out, cb, idxi, out0);
}

// Round 13
// 1412.564 us; speedup vs baseline: 1.3599x; 1.3599x over previous
//
#include <hip/hip_runtime.h>
#include <math.h>

#define B 8
#define D 1024
#define T 4096
#define Q 8
#define K 1024
#define CD 32
#define BT (B * T)

// ---------------- scratch layout inside d_out (bytes) ----------------
// d_out floats [0 .. B*D*T) are scratch until k_gemm_final (last kernel) writes them.
// k_gemm_final reads ONLY inputs + idxi (in d_ws) -> no overlap hazard.
#define OFF_Z0   ((size_t)0)                            // f64 [Q][B][CD][T]  64 MB
#define OFF_MT   (OFF_Z0 + (size_t)Q * B * CD * T * 8)  // f64 [8][8][K][CD]  16 MB
#define OFF_CBN  (OFF_MT + (size_t)64 * K * CD * 8)     // f64 [Q][K][CD]      2 MB
#define OFF_N264 (OFF_CBN + (size_t)Q * K * CD * 8)     // f64 [Q][K]         64 KB
#define OFF_NT   (OFF_N264 + (size_t)Q * K * 8)         // f64 [64][CD][CD]  512 KB
#define OFF_BEFF (OFF_NT + (size_t)64 * CD * CD * 8)    // f64 [Q][CD]         2 KB
#define OFF_C32  (OFF_BEFF + (size_t)Q * CD * 8)        // f32 [Q][K][CD]      1 MB
#define OFF_N232 (OFF_C32 + (size_t)Q * K * CD * 4)     // f32 [Q][K]         32 KB
#define OFF_W64  (OFF_N232 + (size_t)Q * K * 4)         // f64 [Q][CD][D]      2 MB
// idxi i32 [Q][BT] lives in d_ws @ 0 (1 MB)

__global__ void k_zero_losses(float* __restrict__ loss) {
    if (threadIdx.x < Q) loss[threadIdx.x] = 0.0f;
}

// Normalize codebooks fp64 + fp32 copies for the prefilter.
__global__ __launch_bounds__(256) void k_norm(const float* __restrict__ cb,
                                              double* __restrict__ cbn64,
                                              double* __restrict__ n264,
                                              float* __restrict__ cbn32,
                                              float* __restrict__ n232) {
    int i = blockIdx.x * 256 + threadIdx.x;   // 0..Q*K-1
    const float* c = cb + (size_t)i * CD;
    double v[CD];
    double ss = 0.0;
#pragma unroll
    for (int j = 0; j < CD; ++j) { v[j] = (double)c[j]; ss += v[j] * v[j]; }
    double s = 1.0 / sqrt(ss + 1e-12);
    double n2 = 0.0;
    double* o = cbn64 + (size_t)i * CD;
    float* o32 = cbn32 + (size_t)i * CD;
#pragma unroll
    for (int j = 0; j < CD; ++j) {
        double vn = v[j] * s;
        o[j] = vn; o32[j] = (float)vn; n2 += vn * vn;
    }
    n264[i] = n2; n232[i] = (float)n2;
}

// Win -> fp64 copy
__global__ __launch_bounds__(256) void k_cvtW(const float* __restrict__ Win,
                                              double* __restrict__ Win64) {
    int i = blockIdx.x * 256 + threadIdx.x;
    Win64[i] = (double)Win[i];
}

// N[q][j][c][c'] = sum_d Win_q[c,d] * Wout_j[d,c']   (fp64)
__global__ __launch_bounds__(256) void k_prep_N(const float* __restrict__ Win,
                                                const float* __restrict__ Wout,
                                                double* __restrict__ Ntab) {
    const int q = blockIdx.x >> 3, j = blockIdx.x & 7;
    __shared__ float a_sh[CD][128];
    __shared__ float b_sh[128][CD];
    double acc[4] = {0.0, 0.0, 0.0, 0.0};
    for (int d0 = 0; d0 < D; d0 += 128) {
        __syncthreads();
        for (int i = threadIdx.x; i < CD * 128; i += 256) {
            int cc = i >> 7, dl = i & 127;
            a_sh[cc][dl] = Win[((size_t)q * CD + cc) * D + d0 + dl];
        }
        for (int i = threadIdx.x; i < 128 * CD; i += 256) {
            int dl = i >> 5, cc = i & 31;
            b_sh[dl][cc] = Wout[((size_t)j * D + d0 + dl) * CD + cc];
        }
        __syncthreads();
        for (int dl = 0; dl < 128; ++dl) {
#pragma unroll
            for (int r = 0; r < 4; ++r) {
                int i = r * 256 + threadIdx.x;
                acc[r] = fma((double)a_sh[i >> 5][dl], (double)b_sh[dl][i & 31], acc[r]);
            }
        }
    }
#pragma unroll
    for (int r = 0; r < 4; ++r) {
        int i = r * 256 + threadIdx.x;
        Ntab[((size_t)(q * 8 + j) * CD + (i >> 5)) * CD + (i & 31)] = acc[r];
    }
}

// M[q][j][k][c] = sum_c' N[q][j][c][c'] * cb_j[k][c']   (fp64)
__global__ __launch_bounds__(256) void k_prep_M(const float* __restrict__ cb,
                                                const double* __restrict__ Ntab,
                                                double* __restrict__ Mt) {
    const int q = blockIdx.z, j = blockIdx.y;
    const int k = blockIdx.x * 256 + threadIdx.x;
    __shared__ double nsh[CD][CD];
    for (int i = threadIdx.x; i < CD * CD; i += 256)
        nsh[i >> 5][i & 31] = Ntab[(size_t)(q * 8 + j) * CD * CD + i];
    __syncthreads();
    double cv[CD];
    const float* cr = cb + ((size_t)j * K + k) * CD;
#pragma unroll
    for (int c = 0; c < CD; ++c) cv[c] = (double)cr[c];
    double* mo = Mt + (((size_t)(q * 8 + j) * K + k) * CD);
#pragma unroll
    for (int c = 0; c < CD; ++c) {
        double a = 0.0;
#pragma unroll
        for (int cp = 0; cp < CD; ++cp) a = fma(nsh[c][cp], cv[cp], a);
        mo[c] = a;
    }
}

// beff[q][c] = b_in[q][c] - sum_d Win_q[c][d] * (sum_{j<q} b_out[j][d])
__global__ __launch_bounds__(256) void k_prep_beff(const float* __restrict__ Win,
                                                   const float* __restrict__ b_in,
                                                   const float* __restrict__ b_out,
                                                   double* __restrict__ beff) {
    const int c = blockIdx.x, q = blockIdx.y;
    __shared__ double red[256];
    double p = 0.0;
    for (int d = threadIdx.x; d < D; d += 256) {
        double bp = 0.0;
        for (int j = 0; j < q; ++j) bp += (double)b_out[j * D + d];
        p = fma((double)Win[((size_t)q * CD + c) * D + d], bp, p);
    }
    red[threadIdx.x] = p;
    __syncthreads();
    for (int s = 128; s > 0; s >>= 1) {
        if (threadIdx.x < s) red[threadIdx.x] += red[threadIdx.x + s];
        __syncthreads();
    }
    if (threadIdx.x == 0) beff[q * CD + c] = (double)b_in[q * CD + c] - red[0];
}

// z0[q][b][c][t] = beff[q][c] + sum_d Win_q[c][d] * x[b][d][t]  (fp64)
// Round-10 proven version: 1 t/thread, CD split across blockIdx.y (2 halves).
// acc[16] ~56 VGPR, no spill. Per-channel chain order identical -> z0 bit-identical.
__global__ __launch_bounds__(256, 4) void k_gemmZ(const float* __restrict__ x,
                                                  const double* __restrict__ Win64,
                                                  const double* __restrict__ beff,
                                                  double* __restrict__ z0) {
    int h = blockIdx.x;
    int u = h >> 3, r = h & 7;
    int q = u & 7;
    int m = r + 8 * (u >> 3);
    int b = m >> 4;
    int tc = m & 15;
    int t = tc * 256 + threadIdx.x;
    const int c0 = blockIdx.y * (CD / 2);

    const double* w = Win64 + ((size_t)q * CD + c0) * D;
    const double* be = beff + q * CD + c0;
    const float* xb = x + (size_t)b * D * T + t;

    double acc[CD / 2];
#pragma unroll
    for (int c = 0; c < CD / 2; ++c) acc[c] = be[c];

    for (int d0 = 0; d0 < D; d0 += 8) {
        double xv[8];
#pragma unroll
        for (int i = 0; i < 8; ++i) xv[i] = (double)xb[(size_t)(d0 + i) * T];
#pragma unroll
        for (int c = 0; c < CD / 2; ++c) {
            const double* wc = w + (size_t)c * D + d0;
#pragma unroll
            for (int i = 0; i < 8; ++i) acc[c] = fma(wc[i], xv[i], acc[c]);
        }
    }
    double* zo = z0 + (((size_t)q * B + b) * CD + c0) * T + t;
#pragma unroll
    for (int c = 0; c < CD / 2; ++c) zo[(size_t)c * T] = acc[c];
}

// insert (dd,ii) into sorted top-4 (d1<=d2<=d3<=d4)
#define INS4(dd, ii)                                                           \
    do {                                                                       \
        float _d = (dd); int _i = (ii);                                        \
        if (_d < d4) {                                                         \
            d4 = _d; i4 = _i;                                                  \
            if (d4 < d3) { float tf = d3; d3 = d4; d4 = tf; int ti = i3; i3 = i4; i4 = ti; } \
            if (d3 < d2) { float tf = d2; d2 = d3; d3 = tf; int ti = i2; i2 = i3; i3 = ti; } \
            if (d2 < d1) { float tf = d1; d1 = d2; d2 = tf; int ti = i1; i1 = i2; i2 = ti; } \
        }                                                                      \
    } while (0)

// ---------- fused 8-stage argmin, 8-wave blocks (round-10 proven version) ----------
#define AT 64
#define NW 8
#define KPW (K / NW)
__global__ __launch_bounds__(512) void k_argmin_fused(const double* __restrict__ z0,
                                                      const double* __restrict__ Mt,
                                                      const double* __restrict__ cbn64,
                                                      const double* __restrict__ n264,
                                                      const float* __restrict__ cbn32,
                                                      const float* __restrict__ n232,
                                                      const float* __restrict__ cb,
                                                      int* __restrict__ idxi,
                                                      float* __restrict__ idx_f,
                                                      float* __restrict__ loss) {
    const int lane = threadIdx.x & 63;
    const int wv = threadIdx.x >> 6;                        // 0..7
    const int kcw = __builtin_amdgcn_readfirstlane(wv);     // uniform wave id
    const int t = blockIdx.x * AT + lane;
    const int b = blockIdx.y;
    const size_t bt = (size_t)b * T + t;

    __shared__ double zn_s[CD][AT];       // 16 KB (RAW z, fp64)
    __shared__ float  sd[NW][4][AT];      //  8 KB
    __shared__ int    si[NW][4][AT];      //  8 KB
    __shared__ double ed[4][AT];          //  2 KB (candidate fp64 dists)
    __shared__ int    hist_s[Q][AT];      //  2 KB

    for (int q = 0; q < Q; ++q) {
        // ---- Phase A: distributed reconstruct (exact j-ascending chain per channel) ----
        {
            const int c0 = wv * 4;
            const double* zb = z0 + (((size_t)q * B + b) * CD + c0) * T + t;
            double v0 = zb[0];
            double v1 = zb[(size_t)T];
            double v2 = zb[(size_t)2 * T];
            double v3 = zb[(size_t)3 * T];
            for (int j = 0; j < q; ++j) {
                int kj = hist_s[j][lane];
                const double* m = Mt + (((size_t)(q * 8 + j) * K + kj) * CD) + c0;
                v0 -= m[0];
                v1 -= m[1];
                v2 -= m[2];
                v3 -= m[3];
            }
            zn_s[c0][lane] = v0;
            zn_s[c0 + 1][lane] = v1;
            zn_s[c0 + 2][lane] = v2;
            zn_s[c0 + 3][lane] = v3;
        }
        __syncthreads();

        // ---- Phase C: per-wave local normalize (bit-identical) + fp32 top-4 scan ----
        double s, rnorm;
        float d1 = 1e30f, d2 = 1e30f, d3 = 1e30f, d4 = 1e30f;
        int i1 = 0, i2 = 0, i3 = 0, i4 = 0;
        {
            double ss = 0.0;
#pragma unroll
            for (int c = 0; c < CD; ++c) { double v = zn_s[c][lane]; ss += v * v; }
            rnorm = sqrt(ss + 1e-12);
            s = 1.0 / rnorm;
            float znf[CD];
            float a2 = 0.0f;
#pragma unroll
            for (int c = 0; c < CD; ++c) {
                double vn = zn_s[c][lane] * s;
                float zf = (float)vn;
                znf[c] = zf;
                a2 = fmaf(zf, zf, a2);
            }

            const float4* cp = (const float4*)(cbn32 + ((size_t)q * K + (size_t)kcw * KPW) * CD);
            const float* nq = n232 + q * K + kcw * KPW;
            for (int k = 0; k < KPW; k += 4) {
                const float4* c0 = cp + k * (CD / 4);
                float p0 = 0.f, p1 = 0.f, p2 = 0.f, p3 = 0.f;
                float r0 = 0.f, r1 = 0.f, r2 = 0.f, r3 = 0.f;
                float s0 = 0.f, s1 = 0.f, s2 = 0.f, s3 = 0.f;
                float u0 = 0.f, u1 = 0.f, u2 = 0.f, u3 = 0.f;
#pragma unroll
                for (int u = 0; u < CD / 4; ++u) {
                    float4 av = c0[u];
                    float4 bv = c0[u + 8];
                    float4 cv = c0[u + 16];
                    float4 dv = c0[u + 24];
                    float z0f = znf[u * 4 + 0], z1f = znf[u * 4 + 1];
                    float z2f = znf[u * 4 + 2], z3f = znf[u * 4 + 3];
                    p0 = fmaf(z0f, av.x, p0); p1 = fmaf(z1f, av.y, p1);
                    p2 = fmaf(z2f, av.z, p2); p3 = fmaf(z3f, av.w, p3);
                    r0 = fmaf(z0f, bv.x, r0); r1 = fmaf(z1f, bv.y, r1);
                    r2 = fmaf(z2f, bv.z, r2); r3 = fmaf(z3f, bv.w, r3);
                    s0 = fmaf(z0f, cv.x, s0); s1 = fmaf(z1f, cv.y, s1);
                    s2 = fmaf(z2f, cv.z, s2); s3 = fmaf(z3f, cv.w, s3);
                    u0 = fmaf(z0f, dv.x, u0); u1 = fmaf(z1f, dv.y, u1);
                    u2 = fmaf(z2f, dv.z, u2); u3 = fmaf(z3f, dv.w, u3);
                }
                float dist0 = fmaf(-2.0f, (p0 + p1) + (p2 + p3), a2) + nq[k];
                float dist1 = fmaf(-2.0f, (r0 + r1) + (r2 + r3), a2) + nq[k + 1];
                float dist2 = fmaf(-2.0f, (s0 + s1) + (s2 + s3), a2) + nq[k + 2];
                float dist3 = fmaf(-2.0f, (u0 + u1) + (u2 + u3), a2) + nq[k + 3];
                INS4(dist0, kcw * KPW + k);
                INS4(dist1, kcw * KPW + k + 1);
                INS4(dist2, kcw * KPW + k + 2);
                INS4(dist3, kcw * KPW + k + 3);
            }
            sd[wv][0][lane] = d1; sd[wv][1][lane] = d2;
            sd[wv][2][lane] = d3; sd[wv][3][lane] = d4;
            si[wv][0][lane] = i1; si[wv][1][lane] = i2;
            si[wv][2][lane] = i3; si[wv][3][lane] = i4;
        }
        __syncthreads();

        // ---- Phase C2: waves 0-3 full merge + conditional distributed fp64 eval ----
        if (wv < 4) {
            d1 = d2 = d3 = d4 = 1e30f; i1 = i2 = i3 = i4 = 0;
            for (int w = 0; w < NW; ++w)
#pragma unroll
                for (int s4 = 0; s4 < 4; ++s4)
                    INS4(sd[w][s4][lane], si[w][s4][lane]);

            // eval needed only in the band gap2 < 1e-4 <= gap4
            if (d2 - d1 < 1e-4f && d4 - d1 >= 1e-4f) {
                int j1 = i1, j2 = i2, j3 = i3, j4 = i4;
                { int tt; if (j1 > j2) { tt = j1; j1 = j2; j2 = tt; }
                          if (j3 > j4) { tt = j3; j3 = j4; j4 = tt; }
                          if (j1 > j3) { tt = j1; j1 = j3; j3 = tt; }
                          if (j2 > j4) { tt = j2; j2 = j4; j4 = tt; }
                          if (j2 > j3) { tt = j2; j2 = j3; j3 = tt; } }
                const int myj = (wv == 0) ? j1 : (wv == 1) ? j2 : (wv == 2) ? j3 : j4;
                const double* cp64 = cbn64 + ((size_t)q * K + myj) * CD;
                double A = 0.0, dot = 0.0;
#pragma unroll
                for (int c = 0; c < CD; ++c) {
                    double vn = zn_s[c][lane] * s;    // identical bits to round-5 zn
                    A += vn * vn;
                    dot = fma(vn, cp64[c], dot);
                }
                ed[wv][lane] = (A - 2.0 * dot) + n264[(size_t)q * K + myj];
            }
        }
        __syncthreads();

        // ---- Phase D: wave 0 final pick + loss + writes ----
        if (wv == 0) {
            int bi;
            if (d2 - d1 >= 1e-4f) {
                bi = i1;                      // provably the fp64 argmin
            } else if (d4 - d1 >= 1e-4f) {
                int j1 = i1, j2 = i2, j3 = i3, j4 = i4;
                { int tt; if (j1 > j2) { tt = j1; j1 = j2; j2 = tt; }
                          if (j3 > j4) { tt = j3; j3 = j4; j4 = tt; }
                          if (j1 > j3) { tt = j1; j1 = j3; j3 = tt; }
                          if (j2 > j4) { tt = j2; j2 = j4; j4 = tt; }
                          if (j2 > j3) { tt = j2; j2 = j3; j3 = tt; } }
                double e1 = ed[0][lane], e2 = ed[1][lane];
                double e3 = ed[2][lane], e4 = ed[3][lane];
                double best = e1; bi = j1;
                if (e2 < best) { best = e2; bi = j2; }
                if (e3 < best) { best = e3; bi = j3; }
                if (e4 < best) { best = e4; bi = j4; }
            } else {
                // rare full fp64 rescan (exact round-1 formula; 2-code ILP)
                double zn[CD]; double A = 0.0;
#pragma unroll
                for (int c = 0; c < CD; ++c) {
                    zn[c] = zn_s[c][lane] * s;
                    A += zn[c] * zn[c];
                }
                double best = 1e300; bi = 0;
                const double* cq64 = cbn64 + (size_t)q * K * CD;
                const double* nq64 = n264 + (size_t)q * K;
                for (int k = 0; k < K; k += 2) {
                    double dot0 = 0.0, dot1 = 0.0;
                    const double* c0 = cq64 + (size_t)k * CD;
                    const double* c1 = c0 + CD;
#pragma unroll
                    for (int c = 0; c < CD; ++c) {
                        dot0 = fma(zn[c], c0[c], dot0);
                        dot1 = fma(zn[c], c1[c], dot1);
                    }
                    double dist0 = (A - 2.0 * dot0) + nq64[k];
                    double dist1 = (A - 2.0 * dot1) + nq64[k + 1];
                    if (dist0 < best) { best = dist0; bi = k; }
                    if (dist1 < best) { best = dist1; bi = k + 1; }
                }
            }
            hist_s[q][lane] = bi;

            const float* cr = cb + ((size_t)q * K + bi) * CD;
            double sq = 0.0;
#pragma unroll
            for (int c = 0; c < CD; ++c) {
                double vn = zn_s[c][lane] * s;                    // = round-5 zn bits
                double diff = vn * rnorm - (double)cr[c];         // round-1 loss form
                sq = fma(diff, diff, sq);
            }
#pragma unroll
            for (int off = 32; off > 0; off >>= 1) sq += __shfl_down(sq, off);
            if (lane == 0)
                atomicAdd(&loss[q], (float)(sq * (1.25 / (double)((size_t)B * CD * T))));
            idxi[q * BT + bt] = bi;
            idx_f[(size_t)q * BT + bt] = (float)bi;
        }
        __syncthreads();   // WAR: zn_s/sd/si/ed reused; hist_s visible to Phase A
    }
}

// ---------- k_final as register-blocked fp32 GEMM, T14 stage-split (r12 proven) ----------
#define GT 128
#define GD 128
__global__ __launch_bounds__(256) void k_gemm_final(const float* __restrict__ Wout,
                                                    const float* __restrict__ bo,
                                                    const float* __restrict__ cb,
                                                    const int* __restrict__ idxi,
                                                    float* __restrict__ out) {
    const int t0 = blockIdx.x * GT;
    const int b  = blockIdx.y;
    const int d0 = blockIdx.z * GD;
    const int tx = threadIdx.x & 15;
    const int ty = threadIdx.x >> 4;
    __shared__ float Wt[CD][GD + 4];
    __shared__ float Zt[CD][GT + 4];
    __shared__ float bsum[GD];

    if (threadIdx.x < GD) {
        float sjb = 0.0f;
#pragma unroll
        for (int j = 0; j < Q; ++j) sjb += bo[j * D + d0 + threadIdx.x];
        bsum[threadIdx.x] = sjb;
    }

    float acc[8][8];
#pragma unroll
    for (int r = 0; r < 8; ++r)
#pragma unroll
        for (int cc = 0; cc < 8; ++cc) acc[r][cc] = 0.0f;

    for (int j = 0; j < Q; ++j) {
        // prefetch staging data into registers (no LDS touch -> safe pre-barrier)
        float4 wv[4], zv[4];
#pragma unroll
        for (int r = 0; r < 4; ++r) {
            int i4 = threadIdx.x + r * 256;            // float4 idx, 0..1023
            wv[r] = ((const float4*)(Wout + ((size_t)j * D + d0) * CD))[i4];
            int rowi = i4 >> 3;                        // 0..127
            int kj = idxi[j * BT + (size_t)b * T + t0 + rowi];
            zv[r] = ((const float4*)(cb + ((size_t)j * K + kj) * CD))[i4 & 7];
        }
        __syncthreads();   // WAR: previous iter's reads of Wt/Zt done
#pragma unroll
        for (int r = 0; r < 4; ++r) {
            int i4 = threadIdx.x + r * 256;
            int rowi = i4 >> 3;
            int cq = (i4 & 7) * 4;
            Wt[cq][rowi] = wv[r].x; Wt[cq + 1][rowi] = wv[r].y;
            Wt[cq + 2][rowi] = wv[r].z; Wt[cq + 3][rowi] = wv[r].w;
            Zt[cq][rowi] = zv[r].x; Zt[cq + 1][rowi] = zv[r].y;
            Zt[cq + 2][rowi] = zv[r].z; Zt[cq + 3][rowi] = zv[r].w;
        }
        __syncthreads();
#pragma unroll
        for (int k = 0; k < CD; ++k) {
            float a[8], zb[8];
            *(float4*)&a[0]  = *(const float4*)&Wt[k][ty * 8];
            *(float4*)&a[4]  = *(const float4*)&Wt[k][ty * 8 + 4];
            *(float4*)&zb[0] = *(const float4*)&Zt[k][tx * 8];
            *(float4*)&zb[4] = *(const float4*)&Zt[k][tx * 8 + 4];
#pragma unroll
            for (int r = 0; r < 8; ++r)
#pragma unroll
                for (int cc = 0; cc < 8; ++cc)
                    acc[r][cc] = fmaf(a[r], zb[cc], acc[r][cc]);
        }
    }
#pragma unroll
    for (int r = 0; r < 8; ++r) {
        const int d = d0 + ty * 8 + r;
        const float bias = bsum[ty * 8 + r];
        float4 v0, v1;
        v0.x = acc[r][0] + bias; v0.y = acc[r][1] + bias;
        v0.z = acc[r][2] + bias; v0.w = acc[r][3] + bias;
        v1.x = acc[r][4] + bias; v1.y = acc[r][5] + bias;
        v1.z = acc[r][6] + bias; v1.w = acc[r][7] + bias;
        float* op = out + ((size_t)b * D + d) * T + t0 + tx * 8;
        *(float4*)op = v0;
        *(float4*)(op + 4) = v1;
    }
}

extern "C" void kernel_launch(void* const* d_in, const int* in_sizes, int n_in,
                              void* d_out, int out_size, void* d_ws, size_t ws_size,
                              hipStream_t stream) {
    const float* x     = (const float*)d_in[0];
    const float* Win   = (const float*)d_in[1];
    const float* b_in  = (const float*)d_in[2];
    const float* Wout  = (const float*)d_in[3];
    const float* b_out = (const float*)d_in[4];
    const float* cb    = (const float*)d_in[5];

    float* out0  = (float*)d_out;
    float* idx_f = out0 + (size_t)B * D * T;
    float* loss  = idx_f + (size_t)Q * BT;

    char* sc = (char*)d_out;   // scratch: dead before k_gemm_final writes out0
    double* z0    = (double*)(sc + OFF_Z0);
    double* Mt    = (double*)(sc + OFF_MT);
    double* cbn64 = (double*)(sc + OFF_CBN);
    double* n264  = (double*)(sc + OFF_N264);
    double* Ntab  = (double*)(sc + OFF_NT);
    double* beff  = (double*)(sc + OFF_BEFF);
    float*  cbn32 = (float*)(sc + OFF_C32);
    float*  n232  = (float*)(sc + OFF_N232);
    double* Win64 = (double*)(sc + OFF_W64);
    int*    idxi  = (int*)d_ws;                  // 1 MB, safe for gemm_final

    k_zero_losses<<<1, 64, 0, stream>>>(loss);
    k_norm<<<(Q * K) / 256, 256, 0, stream>>>(cb, cbn64, n264, cbn32, n232);
    k_cvtW<<<(Q * CD * D) / 256, 256, 0, stream>>>(Win, Win64);
    k_prep_N<<<64, 256, 0, stream>>>(Win, Wout, Ntab);
    k_prep_M<<<dim3(K / 256, 8, 8), 256, 0, stream>>>(cb, Ntab, Mt);
    k_prep_beff<<<dim3(CD, Q), 256, 0, stream>>>(Win, b_in, b_out, beff);

    k_gemmZ<<<dim3(Q * B * (T / 256), 2), 256, 0, stream>>>(x, Win64, beff, z0);

    k_argmin_fused<<<dim3(T / AT, B), 512, 0, stream>>>(z0, Mt, cbn64, n264,
                                                        cbn32, n232, cb,
                                                        idxi, idx_f, loss);

    k_gemm_final<<<dim3(T / GT, B, D / GD), 256, 0, stream>>>(Wout, b_out, cb, idxi, out0);
}

// Round 14
// 1276.162 us; speedup vs baseline: 1.5053x; 1.1069x over previous
//
#include <hip/hip_runtime.h>
#include <math.h>

#define B 8
#define D 1024
#define T 4096
#define Q 8
#define K 1024
#define CD 32
#define BT (B * T)

// ---------------- scratch layout inside d_out (bytes) ----------------
// d_out floats [0 .. B*D*T) are scratch until k_gemm_final (last kernel) writes them.
// k_gemm_final reads ONLY inputs + idxi (in d_ws) -> no overlap hazard.
#define OFF_Z0   ((size_t)0)                            // f64 [Q][B][CD][T]  64 MB
#define OFF_MT   (OFF_Z0 + (size_t)Q * B * CD * T * 8)  // f64 [8][8][K][CD]  16 MB
#define OFF_CBN  (OFF_MT + (size_t)64 * K * CD * 8)     // f64 [Q][K][CD]      2 MB
#define OFF_N264 (OFF_CBN + (size_t)Q * K * CD * 8)     // f64 [Q][K]         64 KB
#define OFF_NT   (OFF_N264 + (size_t)Q * K * 8)         // f64 [64][CD][CD]  512 KB
#define OFF_BEFF (OFF_NT + (size_t)64 * CD * CD * 8)    // f64 [Q][CD]         2 KB
#define OFF_C32  (OFF_BEFF + (size_t)Q * CD * 8)        // f32 [Q][K][CD]      1 MB
#define OFF_N232 (OFF_C32 + (size_t)Q * K * CD * 4)     // f32 [Q][K]         32 KB
#define OFF_W64  (OFF_N232 + (size_t)Q * K * 4)         // f64 [Q][CD][D]      2 MB
// idxi i32 [Q][BT] lives in d_ws @ 0 (1 MB)

__global__ void k_zero_losses(float* __restrict__ loss) {
    if (threadIdx.x < Q) loss[threadIdx.x] = 0.0f;
}

// Normalize codebooks fp64 + fp32 copies for the prefilter.
__global__ __launch_bounds__(256) void k_norm(const float* __restrict__ cb,
                                              double* __restrict__ cbn64,
                                              double* __restrict__ n264,
                                              float* __restrict__ cbn32,
                                              float* __restrict__ n232) {
    int i = blockIdx.x * 256 + threadIdx.x;   // 0..Q*K-1
    const float* c = cb + (size_t)i * CD;
    double v[CD];
    double ss = 0.0;
#pragma unroll
    for (int j = 0; j < CD; ++j) { v[j] = (double)c[j]; ss += v[j] * v[j]; }
    double s = 1.0 / sqrt(ss + 1e-12);
    double n2 = 0.0;
    double* o = cbn64 + (size_t)i * CD;
    float* o32 = cbn32 + (size_t)i * CD;
#pragma unroll
    for (int j = 0; j < CD; ++j) {
        double vn = v[j] * s;
        o[j] = vn; o32[j] = (float)vn; n2 += vn * vn;
    }
    n264[i] = n2; n232[i] = (float)n2;
}

// Win -> fp64 copy
__global__ __launch_bounds__(256) void k_cvtW(const float* __restrict__ Win,
                                              double* __restrict__ Win64) {
    int i = blockIdx.x * 256 + threadIdx.x;
    Win64[i] = (double)Win[i];
}

// N[q][j][c][c'] = sum_d Win_q[c,d] * Wout_j[d,c']   (fp64)
__global__ __launch_bounds__(256) void k_prep_N(const float* __restrict__ Win,
                                                const float* __restrict__ Wout,
                                                double* __restrict__ Ntab) {
    const int q = blockIdx.x >> 3, j = blockIdx.x & 7;
    __shared__ float a_sh[CD][128];
    __shared__ float b_sh[128][CD];
    double acc[4] = {0.0, 0.0, 0.0, 0.0};
    for (int d0 = 0; d0 < D; d0 += 128) {
        __syncthreads();
        for (int i = threadIdx.x; i < CD * 128; i += 256) {
            int cc = i >> 7, dl = i & 127;
            a_sh[cc][dl] = Win[((size_t)q * CD + cc) * D + d0 + dl];
        }
        for (int i = threadIdx.x; i < 128 * CD; i += 256) {
            int dl = i >> 5, cc = i & 31;
            b_sh[dl][cc] = Wout[((size_t)j * D + d0 + dl) * CD + cc];
        }
        __syncthreads();
        for (int dl = 0; dl < 128; ++dl) {
#pragma unroll
            for (int r = 0; r < 4; ++r) {
                int i = r * 256 + threadIdx.x;
                acc[r] = fma((double)a_sh[i >> 5][dl], (double)b_sh[dl][i & 31], acc[r]);
            }
        }
    }
#pragma unroll
    for (int r = 0; r < 4; ++r) {
        int i = r * 256 + threadIdx.x;
        Ntab[((size_t)(q * 8 + j) * CD + (i >> 5)) * CD + (i & 31)] = acc[r];
    }
}

// M[q][j][k][c] = sum_c' N[q][j][c][c'] * cb_j[k][c']   (fp64)
__global__ __launch_bounds__(256) void k_prep_M(const float* __restrict__ cb,
                                                const double* __restrict__ Ntab,
                                                double* __restrict__ Mt) {
    const int q = blockIdx.z, j = blockIdx.y;
    const int k = blockIdx.x * 256 + threadIdx.x;
    __shared__ double nsh[CD][CD];
    for (int i = threadIdx.x; i < CD * CD; i += 256)
        nsh[i >> 5][i & 31] = Ntab[(size_t)(q * 8 + j) * CD * CD + i];
    __syncthreads();
    double cv[CD];
    const float* cr = cb + ((size_t)j * K + k) * CD;
#pragma unroll
    for (int c = 0; c < CD; ++c) cv[c] = (double)cr[c];
    double* mo = Mt + (((size_t)(q * 8 + j) * K + k) * CD);
#pragma unroll
    for (int c = 0; c < CD; ++c) {
        double a = 0.0;
#pragma unroll
        for (int cp = 0; cp < CD; ++cp) a = fma(nsh[c][cp], cv[cp], a);
        mo[c] = a;
    }
}

// beff[q][c] = b_in[q][c] - sum_d Win_q[c][d] * (sum_{j<q} b_out[j][d])
__global__ __launch_bounds__(256) void k_prep_beff(const float* __restrict__ Win,
                                                   const float* __restrict__ b_in,
                                                   const float* __restrict__ b_out,
                                                   double* __restrict__ beff) {
    const int c = blockIdx.x, q = blockIdx.y;
    __shared__ double red[256];
    double p = 0.0;
    for (int d = threadIdx.x; d < D; d += 256) {
        double bp = 0.0;
        for (int j = 0; j < q; ++j) bp += (double)b_out[j * D + d];
        p = fma((double)Win[((size_t)q * CD + c) * D + d], bp, p);
    }
    red[threadIdx.x] = p;
    __syncthreads();
    for (int s = 128; s > 0; s >>= 1) {
        if (threadIdx.x < s) red[threadIdx.x] += red[threadIdx.x + s];
        __syncthreads();
    }
    if (threadIdx.x == 0) beff[q * CD + c] = (double)b_in[q * CD + c] - red[0];
}

// z0[q][b][c][t] = beff[q][c] + sum_d Win_q[c][d] * x[b][d][t]  (fp64)
// Round-7 proven full-CD version: 1 t/thread, all 32 channels per block
// (x read ONCE; 8 consecutive blocks share q -> weights hit constant cache).
// Per-channel chain order identical to rounds 3-13 -> z0 bit-identical.
__global__ __launch_bounds__(256) void k_gemmZ(const float* __restrict__ x,
                                               const double* __restrict__ Win64,
                                               const double* __restrict__ beff,
                                               double* __restrict__ z0) {
    int h = blockIdx.x;
    int u = h >> 3, r = h & 7;
    int q = u & 7;
    int m = r + 8 * (u >> 3);
    int b = m >> 4;
    int tc = m & 15;
    int t = tc * 256 + threadIdx.x;

    const double* w = Win64 + (size_t)q * CD * D;
    const double* be = beff + q * CD;
    const float* xb = x + (size_t)b * D * T + t;

    double acc[CD];
#pragma unroll
    for (int c = 0; c < CD; ++c) acc[c] = be[c];

    for (int d0 = 0; d0 < D; d0 += 8) {
        double xv[8];
#pragma unroll
        for (int i = 0; i < 8; ++i) xv[i] = (double)xb[(size_t)(d0 + i) * T];
#pragma unroll
        for (int c = 0; c < CD; ++c) {
            const double* wc = w + (size_t)c * D + d0;
#pragma unroll
            for (int i = 0; i < 8; ++i) acc[c] = fma(wc[i], xv[i], acc[c]);
        }
    }
    double* zo = z0 + (((size_t)q * B + b) * CD) * T + t;
#pragma unroll
    for (int c = 0; c < CD; ++c) zo[(size_t)c * T] = acc[c];
}

// insert (dd,ii) into sorted top-4 (d1<=d2<=d3<=d4)
#define INS4(dd, ii)                                                           \
    do {                                                                       \
        float _d = (dd); int _i = (ii);                                        \
        if (_d < d4) {                                                         \
            d4 = _d; i4 = _i;                                                  \
            if (d4 < d3) { float tf = d3; d3 = d4; d4 = tf; int ti = i3; i3 = i4; i4 = ti; } \
            if (d3 < d2) { float tf = d2; d2 = d3; d3 = tf; int ti = i2; i2 = i3; i3 = ti; } \
            if (d2 < d1) { float tf = d1; d1 = d2; d2 = tf; int ti = i1; i1 = i2; i2 = ti; } \
        }                                                                      \
    } while (0)

// ---------- fused 8-stage argmin, 8-wave blocks (round-10 proven version) ----------
#define AT 64
#define NW 8
#define KPW (K / NW)
__global__ __launch_bounds__(512) void k_argmin_fused(const double* __restrict__ z0,
                                                      const double* __restrict__ Mt,
                                                      const double* __restrict__ cbn64,
                                                      const double* __restrict__ n264,
                                                      const float* __restrict__ cbn32,
                                                      const float* __restrict__ n232,
                                                      const float* __restrict__ cb,
                                                      int* __restrict__ idxi,
                                                      float* __restrict__ idx_f,
                                                      float* __restrict__ loss) {
    const int lane = threadIdx.x & 63;
    const int wv = threadIdx.x >> 6;                        // 0..7
    const int kcw = __builtin_amdgcn_readfirstlane(wv);     // uniform wave id
    const int t = blockIdx.x * AT + lane;
    const int b = blockIdx.y;
    const size_t bt = (size_t)b * T + t;

    __shared__ double zn_s[CD][AT];       // 16 KB (RAW z, fp64)
    __shared__ float  sd[NW][4][AT];      //  8 KB
    __shared__ int    si[NW][4][AT];      //  8 KB
    __shared__ double ed[4][AT];          //  2 KB (candidate fp64 dists)
    __shared__ int    hist_s[Q][AT];      //  2 KB

    for (int q = 0; q < Q; ++q) {
        // ---- Phase A: distributed reconstruct (exact j-ascending chain per channel) ----
        {
            const int c0 = wv * 4;
            const double* zb = z0 + (((size_t)q * B + b) * CD + c0) * T + t;
            double v0 = zb[0];
            double v1 = zb[(size_t)T];
            double v2 = zb[(size_t)2 * T];
            double v3 = zb[(size_t)3 * T];
            for (int j = 0; j < q; ++j) {
                int kj = hist_s[j][lane];
                const double* m = Mt + (((size_t)(q * 8 + j) * K + kj) * CD) + c0;
                v0 -= m[0];
                v1 -= m[1];
                v2 -= m[2];
                v3 -= m[3];
            }
            zn_s[c0][lane] = v0;
            zn_s[c0 + 1][lane] = v1;
            zn_s[c0 + 2][lane] = v2;
            zn_s[c0 + 3][lane] = v3;
        }
        __syncthreads();

        // ---- Phase C: per-wave local normalize (bit-identical) + fp32 top-4 scan ----
        double s, rnorm;
        float d1 = 1e30f, d2 = 1e30f, d3 = 1e30f, d4 = 1e30f;
        int i1 = 0, i2 = 0, i3 = 0, i4 = 0;
        {
            double ss = 0.0;
#pragma unroll
            for (int c = 0; c < CD; ++c) { double v = zn_s[c][lane]; ss += v * v; }
            rnorm = sqrt(ss + 1e-12);
            s = 1.0 / rnorm;
            float znf[CD];
            float a2 = 0.0f;
#pragma unroll
            for (int c = 0; c < CD; ++c) {
                double vn = zn_s[c][lane] * s;
                float zf = (float)vn;
                znf[c] = zf;
                a2 = fmaf(zf, zf, a2);
            }

            const float4* cp = (const float4*)(cbn32 + ((size_t)q * K + (size_t)kcw * KPW) * CD);
            const float* nq = n232 + q * K + kcw * KPW;
            for (int k = 0; k < KPW; k += 4) {
                const float4* c0 = cp + k * (CD / 4);
                float p0 = 0.f, p1 = 0.f, p2 = 0.f, p3 = 0.f;
                float r0 = 0.f, r1 = 0.f, r2 = 0.f, r3 = 0.f;
                float s0 = 0.f, s1 = 0.f, s2 = 0.f, s3 = 0.f;
                float u0 = 0.f, u1 = 0.f, u2 = 0.f, u3 = 0.f;
#pragma unroll
                for (int u = 0; u < CD / 4; ++u) {
                    float4 av = c0[u];
                    float4 bv = c0[u + 8];
                    float4 cv = c0[u + 16];
                    float4 dv = c0[u + 24];
                    float z0f = znf[u * 4 + 0], z1f = znf[u * 4 + 1];
                    float z2f = znf[u * 4 + 2], z3f = znf[u * 4 + 3];
                    p0 = fmaf(z0f, av.x, p0); p1 = fmaf(z1f, av.y, p1);
                    p2 = fmaf(z2f, av.z, p2); p3 = fmaf(z3f, av.w, p3);
                    r0 = fmaf(z0f, bv.x, r0); r1 = fmaf(z1f, bv.y, r1);
                    r2 = fmaf(z2f, bv.z, r2); r3 = fmaf(z3f, bv.w, r3);
                    s0 = fmaf(z0f, cv.x, s0); s1 = fmaf(z1f, cv.y, s1);
                    s2 = fmaf(z2f, cv.z, s2); s3 = fmaf(z3f, cv.w, s3);
                    u0 = fmaf(z0f, dv.x, u0); u1 = fmaf(z1f, dv.y, u1);
                    u2 = fmaf(z2f, dv.z, u2); u3 = fmaf(z3f, dv.w, u3);
                }
                float dist0 = fmaf(-2.0f, (p0 + p1) + (p2 + p3), a2) + nq[k];
                float dist1 = fmaf(-2.0f, (r0 + r1) + (r2 + r3), a2) + nq[k + 1];
                float dist2 = fmaf(-2.0f, (s0 + s1) + (s2 + s3), a2) + nq[k + 2];
                float dist3 = fmaf(-2.0f, (u0 + u1) + (u2 + u3), a2) + nq[k + 3];
                INS4(dist0, kcw * KPW + k);
                INS4(dist1, kcw * KPW + k + 1);
                INS4(dist2, kcw * KPW + k + 2);
                INS4(dist3, kcw * KPW + k + 3);
            }
            sd[wv][0][lane] = d1; sd[wv][1][lane] = d2;
            sd[wv][2][lane] = d3; sd[wv][3][lane] = d4;
            si[wv][0][lane] = i1; si[wv][1][lane] = i2;
            si[wv][2][lane] = i3; si[wv][3][lane] = i4;
        }
        __syncthreads();

        // ---- Phase C2: waves 0-3 full merge + conditional distributed fp64 eval ----
        if (wv < 4) {
            d1 = d2 = d3 = d4 = 1e30f; i1 = i2 = i3 = i4 = 0;
            for (int w = 0; w < NW; ++w)
#pragma unroll
                for (int s4 = 0; s4 < 4; ++s4)
                    INS4(sd[w][s4][lane], si[w][s4][lane]);

            // eval needed only in the band gap2 < 1e-4 <= gap4
            if (d2 - d1 < 1e-4f && d4 - d1 >= 1e-4f) {
                int j1 = i1, j2 = i2, j3 = i3, j4 = i4;
                { int tt; if (j1 > j2) { tt = j1; j1 = j2; j2 = tt; }
                          if (j3 > j4) { tt = j3; j3 = j4; j4 = tt; }
                          if (j1 > j3) { tt = j1; j1 = j3; j3 = tt; }
                          if (j2 > j4) { tt = j2; j2 = j4; j4 = tt; }
                          if (j2 > j3) { tt = j2; j2 = j3; j3 = tt; } }
                const int myj = (wv == 0) ? j1 : (wv == 1) ? j2 : (wv == 2) ? j3 : j4;
                const double* cp64 = cbn64 + ((size_t)q * K + myj) * CD;
                double A = 0.0, dot = 0.0;
#pragma unroll
                for (int c = 0; c < CD; ++c) {
                    double vn = zn_s[c][lane] * s;    // identical bits to round-5 zn
                    A += vn * vn;
                    dot = fma(vn, cp64[c], dot);
                }
                ed[wv][lane] = (A - 2.0 * dot) + n264[(size_t)q * K + myj];
            }
        }
        __syncthreads();

        // ---- Phase D: wave 0 final pick + loss + writes ----
        if (wv == 0) {
            int bi;
            if (d2 - d1 >= 1e-4f) {
                bi = i1;                      // provably the fp64 argmin
            } else if (d4 - d1 >= 1e-4f) {
                int j1 = i1, j2 = i2, j3 = i3, j4 = i4;
                { int tt; if (j1 > j2) { tt = j1; j1 = j2; j2 = tt; }
                          if (j3 > j4) { tt = j3; j3 = j4; j4 = tt; }
                          if (j1 > j3) { tt = j1; j1 = j3; j3 = tt; }
                          if (j2 > j4) { tt = j2; j2 = j4; j4 = tt; }
                          if (j2 > j3) { tt = j2; j2 = j3; j3 = tt; } }
                double e1 = ed[0][lane], e2 = ed[1][lane];
                double e3 = ed[2][lane], e4 = ed[3][lane];
                double best = e1; bi = j1;
                if (e2 < best) { best = e2; bi = j2; }
                if (e3 < best) { best = e3; bi = j3; }
                if (e4 < best) { best = e4; bi = j4; }
            } else {
                // rare full fp64 rescan (exact round-1 formula; 2-code ILP)
                double zn[CD]; double A = 0.0;
#pragma unroll
                for (int c = 0; c < CD; ++c) {
                    zn[c] = zn_s[c][lane] * s;
                    A += zn[c] * zn[c];
                }
                double best = 1e300; bi = 0;
                const double* cq64 = cbn64 + (size_t)q * K * CD;
                const double* nq64 = n264 + (size_t)q * K;
                for (int k = 0; k < K; k += 2) {
                    double dot0 = 0.0, dot1 = 0.0;
                    const double* c0 = cq64 + (size_t)k * CD;
                    const double* c1 = c0 + CD;
#pragma unroll
                    for (int c = 0; c < CD; ++c) {
                        dot0 = fma(zn[c], c0[c], dot0);
                        dot1 = fma(zn[c], c1[c], dot1);
                    }
                    double dist0 = (A - 2.0 * dot0) + nq64[k];
                    double dist1 = (A - 2.0 * dot1) + nq64[k + 1];
                    if (dist0 < best) { best = dist0; bi = k; }
                    if (dist1 < best) { best = dist1; bi = k + 1; }
                }
            }
            hist_s[q][lane] = bi;

            const float* cr = cb + ((size_t)q * K + bi) * CD;
            double sq = 0.0;
#pragma unroll
            for (int c = 0; c < CD; ++c) {
                double vn = zn_s[c][lane] * s;                    // = round-5 zn bits
                double diff = vn * rnorm - (double)cr[c];         // round-1 loss form
                sq = fma(diff, diff, sq);
            }
#pragma unroll
            for (int off = 32; off > 0; off >>= 1) sq += __shfl_down(sq, off);
            if (lane == 0)
                atomicAdd(&loss[q], (float)(sq * (1.25 / (double)((size_t)B * CD * T))));
            idxi[q * BT + bt] = bi;
            idx_f[(size_t)q * BT + bt] = (float)bi;
        }
        __syncthreads();   // WAR: zn_s/sd/si/ed reused; hist_s visible to Phase A
    }
}

// ---------- k_final as register-blocked fp32 GEMM, T14 stage-split (r12 proven) ----------
#define GT 128
#define GD 128
__global__ __launch_bounds__(256) void k_gemm_final(const float* __restrict__ Wout,
                                                    const float* __restrict__ bo,
                                                    const float* __restrict__ cb,
                                                    const int* __restrict__ idxi,
                                                    float* __restrict__ out) {
    const int t0 = blockIdx.x * GT;
    const int b  = blockIdx.y;
    const int d0 = blockIdx.z * GD;
    const int tx = threadIdx.x & 15;
    const int ty = threadIdx.x >> 4;
    __shared__ float Wt[CD][GD + 4];
    __shared__ float Zt[CD][GT + 4];
    __shared__ float bsum[GD];

    if (threadIdx.x < GD) {
        float sjb = 0.0f;
#pragma unroll
        for (int j = 0; j < Q; ++j) sjb += bo[j * D + d0 + threadIdx.x];
        bsum[threadIdx.x] = sjb;
    }

    float acc[8][8];
#pragma unroll
    for (int r = 0; r < 8; ++r)
#pragma unroll
        for (int cc = 0; cc < 8; ++cc) acc[r][cc] = 0.0f;

    for (int j = 0; j < Q; ++j) {
        // prefetch staging data into registers (no LDS touch -> safe pre-barrier)
        float4 wv[4], zv[4];
#pragma unroll
        for (int r = 0; r < 4; ++r) {
            int i4 = threadIdx.x + r * 256;            // float4 idx, 0..1023
            wv[r] = ((const float4*)(Wout + ((size_t)j * D + d0) * CD))[i4];
            int rowi = i4 >> 3;                        // 0..127
            int kj = idxi[j * BT + (size_t)b * T + t0 + rowi];
            zv[r] = ((const float4*)(cb + ((size_t)j * K + kj) * CD))[i4 & 7];
        }
        __syncthreads();   // WAR: previous iter's reads of Wt/Zt done
#pragma unroll
        for (int r = 0; r < 4; ++r) {
            int i4 = threadIdx.x + r * 256;
            int rowi = i4 >> 3;
            int cq = (i4 & 7) * 4;
            Wt[cq][rowi] = wv[r].x; Wt[cq + 1][rowi] = wv[r].y;
            Wt[cq + 2][rowi] = wv[r].z; Wt[cq + 3][rowi] = wv[r].w;
            Zt[cq][rowi] = zv[r].x; Zt[cq + 1][rowi] = zv[r].y;
            Zt[cq + 2][rowi] = zv[r].z; Zt[cq + 3][rowi] = zv[r].w;
        }
        __syncthreads();
#pragma unroll
        for (int k = 0; k < CD; ++k) {
            float a[8], zb[8];
            *(float4*)&a[0]  = *(const float4*)&Wt[k][ty * 8];
            *(float4*)&a[4]  = *(const float4*)&Wt[k][ty * 8 + 4];
            *(float4*)&zb[0] = *(const float4*)&Zt[k][tx * 8];
            *(float4*)&zb[4] = *(const float4*)&Zt[k][tx * 8 + 4];
#pragma unroll
            for (int r = 0; r < 8; ++r)
#pragma unroll
                for (int cc = 0; cc < 8; ++cc)
                    acc[r][cc] = fmaf(a[r], zb[cc], acc[r][cc]);
        }
    }
#pragma unroll
    for (int r = 0; r < 8; ++r) {
        const int d = d0 + ty * 8 + r;
        const float bias = bsum[ty * 8 + r];
        float4 v0, v1;
        v0.x = acc[r][0] + bias; v0.y = acc[r][1] + bias;
        v0.z = acc[r][2] + bias; v0.w = acc[r][3] + bias;
        v1.x = acc[r][4] + bias; v1.y = acc[r][5] + bias;
        v1.z = acc[r][6] + bias; v1.w = acc[r][7] + bias;
        float* op = out + ((size_t)b * D + d) * T + t0 + tx * 8;
        *(float4*)op = v0;
        *(float4*)(op + 4) = v1;
    }
}

extern "C" void kernel_launch(void* const* d_in, const int* in_sizes, int n_in,
                              void* d_out, int out_size, void* d_ws, size_t ws_size,
                              hipStream_t stream) {
    const float* x     = (const float*)d_in[0];
    const float* Win   = (const float*)d_in[1];
    const float* b_in  = (const float*)d_in[2];
    const float* Wout  = (const float*)d_in[3];
    const float* b_out = (const float*)d_in[4];
    const float* cb    = (const float*)d_in[5];

    float* out0  = (float*)d_out;
    float* idx_f = out0 + (size_t)B * D * T;
    float* loss  = idx_f + (size_t)Q * BT;

    char* sc = (char*)d_out;   // scratch: dead before k_gemm_final writes out0
    double* z0    = (double*)(sc + OFF_Z0);
    double* Mt    = (double*)(sc + OFF_MT);
    double* cbn64 = (double*)(sc + OFF_CBN);
    double* n264  = (double*)(sc + OFF_N264);
    double* Ntab  = (double*)(sc + OFF_NT);
    double* beff  = (double*)(sc + OFF_BEFF);
    float*  cbn32 = (float*)(sc + OFF_C32);
    float*  n232  = (float*)(sc + OFF_N232);
    double* Win64 = (double*)(sc + OFF_W64);
    int*    idxi  = (int*)d_ws;                  // 1 MB, safe for gemm_final

    k_zero_losses<<<1, 64, 0, stream>>>(loss);
    k_norm<<<(Q * K) / 256, 256, 0, stream>>>(cb, cbn64, n264, cbn32, n232);
    k_cvtW<<<(Q * CD * D) / 256, 256, 0, stream>>>(Win, Win64);
    k_prep_N<<<64, 256, 0, stream>>>(Win, Wout, Ntab);
    k_prep_M<<<dim3(K / 256, 8, 8), 256, 0, stream>>>(cb, Ntab, Mt);
    k_prep_beff<<<dim3(CD, Q), 256, 0, stream>>>(Win, b_in, b_out, beff);

    k_gemmZ<<<Q * B * (T / 256), 256, 0, stream>>>(x, Win64, beff, z0);

    k_argmin_fused<<<dim3(T / AT, B), 512, 0, stream>>>(z0, Mt, cbn64, n264,
                                                        cbn32, n232, cb,
                                                        idxi, idx_f, loss);

    k_gemm_final<<<dim3(T / GT, B, D / GD), 256, 0, stream>>>(Wout, b_out, cb, idxi, out0);
}

// Round 15
// 1263.743 us; speedup vs baseline: 1.5200x; 1.0098x over previous
//
#include <hip/hip_runtime.h>
#include <math.h>

#define B 8
#define D 1024
#define T 4096
#define Q 8
#define K 1024
#define CD 32
#define BT (B * T)

// ---------------- scratch layout inside d_out (bytes) ----------------
// d_out floats [0 .. B*D*T) are scratch until k_gemm_final (last kernel) writes them.
// k_gemm_final reads ONLY inputs + idxi (in d_ws) -> no overlap hazard.
#define OFF_Z0   ((size_t)0)                            // f64 [Q][B][CD][T]  64 MB
#define OFF_MT   (OFF_Z0 + (size_t)Q * B * CD * T * 8)  // f64 [8][8][K][CD]  16 MB
#define OFF_CBN  (OFF_MT + (size_t)64 * K * CD * 8)     // f64 [Q][K][CD]      2 MB
#define OFF_N264 (OFF_CBN + (size_t)Q * K * CD * 8)     // f64 [Q][K]         64 KB
#define OFF_NT   (OFF_N264 + (size_t)Q * K * 8)         // f64 [64][CD][CD]  512 KB
#define OFF_BEFF (OFF_NT + (size_t)64 * CD * CD * 8)    // f64 [Q][CD]         2 KB
#define OFF_C32  (OFF_BEFF + (size_t)Q * CD * 8)        // f32 [Q][K][CD]      1 MB
#define OFF_N232 (OFF_C32 + (size_t)Q * K * CD * 4)     // f32 [Q][K]         32 KB
#define OFF_W64  (OFF_N232 + (size_t)Q * K * 4)         // f64 [Q][CD][D]      2 MB
// idxi i32 [Q][BT] lives in d_ws @ 0 (1 MB)

__global__ void k_zero_losses(float* __restrict__ loss) {
    if (threadIdx.x < Q) loss[threadIdx.x] = 0.0f;
}

// Normalize codebooks fp64 + fp32 copies for the prefilter.
__global__ __launch_bounds__(256) void k_norm(const float* __restrict__ cb,
                                              double* __restrict__ cbn64,
                                              double* __restrict__ n264,
                                              float* __restrict__ cbn32,
                                              float* __restrict__ n232) {
    int i = blockIdx.x * 256 + threadIdx.x;   // 0..Q*K-1
    const float* c = cb + (size_t)i * CD;
    double v[CD];
    double ss = 0.0;
#pragma unroll
    for (int j = 0; j < CD; ++j) { v[j] = (double)c[j]; ss += v[j] * v[j]; }
    double s = 1.0 / sqrt(ss + 1e-12);
    double n2 = 0.0;
    double* o = cbn64 + (size_t)i * CD;
    float* o32 = cbn32 + (size_t)i * CD;
#pragma unroll
    for (int j = 0; j < CD; ++j) {
        double vn = v[j] * s;
        o[j] = vn; o32[j] = (float)vn; n2 += vn * vn;
    }
    n264[i] = n2; n232[i] = (float)n2;
}

// Win -> fp64 copy
__global__ __launch_bounds__(256) void k_cvtW(const float* __restrict__ Win,
                                              double* __restrict__ Win64) {
    int i = blockIdx.x * 256 + threadIdx.x;
    Win64[i] = (double)Win[i];
}

// N[q][j][c][c'] = sum_d Win_q[c,d] * Wout_j[d,c']   (fp64)
__global__ __launch_bounds__(256) void k_prep_N(const float* __restrict__ Win,
                                                const float* __restrict__ Wout,
                                                double* __restrict__ Ntab) {
    const int q = blockIdx.x >> 3, j = blockIdx.x & 7;
    __shared__ float a_sh[CD][128];
    __shared__ float b_sh[128][CD];
    double acc[4] = {0.0, 0.0, 0.0, 0.0};
    for (int d0 = 0; d0 < D; d0 += 128) {
        __syncthreads();
        for (int i = threadIdx.x; i < CD * 128; i += 256) {
            int cc = i >> 7, dl = i & 127;
            a_sh[cc][dl] = Win[((size_t)q * CD + cc) * D + d0 + dl];
        }
        for (int i = threadIdx.x; i < 128 * CD; i += 256) {
            int dl = i >> 5, cc = i & 31;
            b_sh[dl][cc] = Wout[((size_t)j * D + d0 + dl) * CD + cc];
        }
        __syncthreads();
        for (int dl = 0; dl < 128; ++dl) {
#pragma unroll
            for (int r = 0; r < 4; ++r) {
                int i = r * 256 + threadIdx.x;
                acc[r] = fma((double)a_sh[i >> 5][dl], (double)b_sh[dl][i & 31], acc[r]);
            }
        }
    }
#pragma unroll
    for (int r = 0; r < 4; ++r) {
        int i = r * 256 + threadIdx.x;
        Ntab[((size_t)(q * 8 + j) * CD + (i >> 5)) * CD + (i & 31)] = acc[r];
    }
}

// M[q][j][k][c] = sum_c' N[q][j][c][c'] * cb_j[k][c']   (fp64)
__global__ __launch_bounds__(256) void k_prep_M(const float* __restrict__ cb,
                                                const double* __restrict__ Ntab,
                                                double* __restrict__ Mt) {
    const int q = blockIdx.z, j = blockIdx.y;
    const int k = blockIdx.x * 256 + threadIdx.x;
    __shared__ double nsh[CD][CD];
    for (int i = threadIdx.x; i < CD * CD; i += 256)
        nsh[i >> 5][i & 31] = Ntab[(size_t)(q * 8 + j) * CD * CD + i];
    __syncthreads();
    double cv[CD];
    const float* cr = cb + ((size_t)j * K + k) * CD;
#pragma unroll
    for (int c = 0; c < CD; ++c) cv[c] = (double)cr[c];
    double* mo = Mt + (((size_t)(q * 8 + j) * K + k) * CD);
#pragma unroll
    for (int c = 0; c < CD; ++c) {
        double a = 0.0;
#pragma unroll
        for (int cp = 0; cp < CD; ++cp) a = fma(nsh[c][cp], cv[cp], a);
        mo[c] = a;
    }
}

// beff[q][c] = b_in[q][c] - sum_d Win_q[c][d] * (sum_{j<q} b_out[j][d])
__global__ __launch_bounds__(256) void k_prep_beff(const float* __restrict__ Win,
                                                   const float* __restrict__ b_in,
                                                   const float* __restrict__ b_out,
                                                   double* __restrict__ beff) {
    const int c = blockIdx.x, q = blockIdx.y;
    __shared__ double red[256];
    double p = 0.0;
    for (int d = threadIdx.x; d < D; d += 256) {
        double bp = 0.0;
        for (int j = 0; j < q; ++j) bp += (double)b_out[j * D + d];
        p = fma((double)Win[((size_t)q * CD + c) * D + d], bp, p);
    }
    red[threadIdx.x] = p;
    __syncthreads();
    for (int s = 128; s > 0; s >>= 1) {
        if (threadIdx.x < s) red[threadIdx.x] += red[threadIdx.x + s];
        __syncthreads();
    }
    if (threadIdx.x == 0) beff[q * CD + c] = (double)b_in[q * CD + c] - red[0];
}

// z0[q][b][c][t] = beff[q][c] + sum_d Win_q[c][d] * x[b][d][t]  (fp64)
// r14 full-CD version + register double-buffer of the 8 x-values: chunk d0+8's
// loads are issued BEFORE chunk d0's FMA block, so ~1024 cyc of FMA hide the
// load latency. Per-(c,t) FMA chain order unchanged -> z0 bit-identical.
__global__ __launch_bounds__(256) void k_gemmZ(const float* __restrict__ x,
                                               const double* __restrict__ Win64,
                                               const double* __restrict__ beff,
                                               double* __restrict__ z0) {
    int h = blockIdx.x;
    int u = h >> 3, r = h & 7;
    int q = u & 7;
    int m = r + 8 * (u >> 3);
    int b = m >> 4;
    int tc = m & 15;
    int t = tc * 256 + threadIdx.x;

    const double* w = Win64 + (size_t)q * CD * D;
    const double* be = beff + q * CD;
    const float* xb = x + (size_t)b * D * T + t;

    double acc[CD];
#pragma unroll
    for (int c = 0; c < CD; ++c) acc[c] = be[c];

    double xv[8];
#pragma unroll
    for (int i = 0; i < 8; ++i) xv[i] = (double)xb[(size_t)i * T];

    for (int d0 = 0; d0 < D; d0 += 8) {
        // prefetch next chunk (last iter re-reads current chunk: harmless L1 hit)
        const int nd = (d0 + 8 < D) ? d0 + 8 : d0;
        double xn[8];
#pragma unroll
        for (int i = 0; i < 8; ++i) xn[i] = (double)xb[(size_t)(nd + i) * T];
#pragma unroll
        for (int c = 0; c < CD; ++c) {
            const double* wc = w + (size_t)c * D + d0;
#pragma unroll
            for (int i = 0; i < 8; ++i) acc[c] = fma(wc[i], xv[i], acc[c]);
        }
#pragma unroll
        for (int i = 0; i < 8; ++i) xv[i] = xn[i];
    }
    double* zo = z0 + (((size_t)q * B + b) * CD) * T + t;
#pragma unroll
    for (int c = 0; c < CD; ++c) zo[(size_t)c * T] = acc[c];
}

// insert (dd,ii) into sorted top-4 (d1<=d2<=d3<=d4)
#define INS4(dd, ii)                                                           \
    do {                                                                       \
        float _d = (dd); int _i = (ii);                                        \
        if (_d < d4) {                                                         \
            d4 = _d; i4 = _i;                                                  \
            if (d4 < d3) { float tf = d3; d3 = d4; d4 = tf; int ti = i3; i3 = i4; i4 = ti; } \
            if (d3 < d2) { float tf = d2; d2 = d3; d3 = tf; int ti = i2; i2 = i3; i3 = ti; } \
            if (d2 < d1) { float tf = d1; d1 = d2; d2 = tf; int ti = i1; i1 = i2; i2 = ti; } \
        }                                                                      \
    } while (0)

// ---------- fused 8-stage argmin, 8-wave blocks (round-10 proven version) ----------
#define AT 64
#define NW 8
#define KPW (K / NW)
__global__ __launch_bounds__(512) void k_argmin_fused(const double* __restrict__ z0,
                                                      const double* __restrict__ Mt,
                                                      const double* __restrict__ cbn64,
                                                      const double* __restrict__ n264,
                                                      const float* __restrict__ cbn32,
                                                      const float* __restrict__ n232,
                                                      const float* __restrict__ cb,
                                                      int* __restrict__ idxi,
                                                      float* __restrict__ idx_f,
                                                      float* __restrict__ loss) {
    const int lane = threadIdx.x & 63;
    const int wv = threadIdx.x >> 6;                        // 0..7
    const int kcw = __builtin_amdgcn_readfirstlane(wv);     // uniform wave id
    const int t = blockIdx.x * AT + lane;
    const int b = blockIdx.y;
    const size_t bt = (size_t)b * T + t;

    __shared__ double zn_s[CD][AT];       // 16 KB (RAW z, fp64)
    __shared__ float  sd[NW][4][AT];      //  8 KB
    __shared__ int    si[NW][4][AT];      //  8 KB
    __shared__ double ed[4][AT];          //  2 KB (candidate fp64 dists)
    __shared__ int    hist_s[Q][AT];      //  2 KB

    for (int q = 0; q < Q; ++q) {
        // ---- Phase A: distributed reconstruct (exact j-ascending chain per channel) ----
        {
            const int c0 = wv * 4;
            const double* zb = z0 + (((size_t)q * B + b) * CD + c0) * T + t;
            double v0 = zb[0];
            double v1 = zb[(size_t)T];
            double v2 = zb[(size_t)2 * T];
            double v3 = zb[(size_t)3 * T];
            for (int j = 0; j < q; ++j) {
                int kj = hist_s[j][lane];
                const double* m = Mt + (((size_t)(q * 8 + j) * K + kj) * CD) + c0;
                v0 -= m[0];
                v1 -= m[1];
                v2 -= m[2];
                v3 -= m[3];
            }
            zn_s[c0][lane] = v0;
            zn_s[c0 + 1][lane] = v1;
            zn_s[c0 + 2][lane] = v2;
            zn_s[c0 + 3][lane] = v3;
        }
        __syncthreads();

        // ---- Phase C: per-wave local normalize (bit-identical) + fp32 top-4 scan ----
        double s, rnorm;
        float d1 = 1e30f, d2 = 1e30f, d3 = 1e30f, d4 = 1e30f;
        int i1 = 0, i2 = 0, i3 = 0, i4 = 0;
        {
            double ss = 0.0;
#pragma unroll
            for (int c = 0; c < CD; ++c) { double v = zn_s[c][lane]; ss += v * v; }
            rnorm = sqrt(ss + 1e-12);
            s = 1.0 / rnorm;
            float znf[CD];
            float a2 = 0.0f;
#pragma unroll
            for (int c = 0; c < CD; ++c) {
                double vn = zn_s[c][lane] * s;
                float zf = (float)vn;
                znf[c] = zf;
                a2 = fmaf(zf, zf, a2);
            }

            const float4* cp = (const float4*)(cbn32 + ((size_t)q * K + (size_t)kcw * KPW) * CD);
            const float* nq = n232 + q * K + kcw * KPW;
            for (int k = 0; k < KPW; k += 4) {
                const float4* c0 = cp + k * (CD / 4);
                float p0 = 0.f, p1 = 0.f, p2 = 0.f, p3 = 0.f;
                float r0 = 0.f, r1 = 0.f, r2 = 0.f, r3 = 0.f;
                float s0 = 0.f, s1 = 0.f, s2 = 0.f, s3 = 0.f;
                float u0 = 0.f, u1 = 0.f, u2 = 0.f, u3 = 0.f;
#pragma unroll
                for (int u = 0; u < CD / 4; ++u) {
                    float4 av = c0[u];
                    float4 bv = c0[u + 8];
                    float4 cv = c0[u + 16];
                    float4 dv = c0[u + 24];
                    float z0f = znf[u * 4 + 0], z1f = znf[u * 4 + 1];
                    float z2f = znf[u * 4 + 2], z3f = znf[u * 4 + 3];
                    p0 = fmaf(z0f, av.x, p0); p1 = fmaf(z1f, av.y, p1);
                    p2 = fmaf(z2f, av.z, p2); p3 = fmaf(z3f, av.w, p3);
                    r0 = fmaf(z0f, bv.x, r0); r1 = fmaf(z1f, bv.y, r1);
                    r2 = fmaf(z2f, bv.z, r2); r3 = fmaf(z3f, bv.w, r3);
                    s0 = fmaf(z0f, cv.x, s0); s1 = fmaf(z1f, cv.y, s1);
                    s2 = fmaf(z2f, cv.z, s2); s3 = fmaf(z3f, cv.w, s3);
                    u0 = fmaf(z0f, dv.x, u0); u1 = fmaf(z1f, dv.y, u1);
                    u2 = fmaf(z2f, dv.z, u2); u3 = fmaf(z3f, dv.w, u3);
                }
                float dist0 = fmaf(-2.0f, (p0 + p1) + (p2 + p3), a2) + nq[k];
                float dist1 = fmaf(-2.0f, (r0 + r1) + (r2 + r3), a2) + nq[k + 1];
                float dist2 = fmaf(-2.0f, (s0 + s1) + (s2 + s3), a2) + nq[k + 2];
                float dist3 = fmaf(-2.0f, (u0 + u1) + (u2 + u3), a2) + nq[k + 3];
                INS4(dist0, kcw * KPW + k);
                INS4(dist1, kcw * KPW + k + 1);
                INS4(dist2, kcw * KPW + k + 2);
                INS4(dist3, kcw * KPW + k + 3);
            }
            sd[wv][0][lane] = d1; sd[wv][1][lane] = d2;
            sd[wv][2][lane] = d3; sd[wv][3][lane] = d4;
            si[wv][0][lane] = i1; si[wv][1][lane] = i2;
            si[wv][2][lane] = i3; si[wv][3][lane] = i4;
        }
        __syncthreads();

        // ---- Phase C2: waves 0-3 full merge + conditional distributed fp64 eval ----
        if (wv < 4) {
            d1 = d2 = d3 = d4 = 1e30f; i1 = i2 = i3 = i4 = 0;
            for (int w = 0; w < NW; ++w)
#pragma unroll
                for (int s4 = 0; s4 < 4; ++s4)
                    INS4(sd[w][s4][lane], si[w][s4][lane]);

            // eval needed only in the band gap2 < 1e-4 <= gap4
            if (d2 - d1 < 1e-4f && d4 - d1 >= 1e-4f) {
                int j1 = i1, j2 = i2, j3 = i3, j4 = i4;
                { int tt; if (j1 > j2) { tt = j1; j1 = j2; j2 = tt; }
                          if (j3 > j4) { tt = j3; j3 = j4; j4 = tt; }
                          if (j1 > j3) { tt = j1; j1 = j3; j3 = tt; }
                          if (j2 > j4) { tt = j2; j2 = j4; j4 = tt; }
                          if (j2 > j3) { tt = j2; j2 = j3; j3 = tt; } }
                const int myj = (wv == 0) ? j1 : (wv == 1) ? j2 : (wv == 2) ? j3 : j4;
                const double* cp64 = cbn64 + ((size_t)q * K + myj) * CD;
                double A = 0.0, dot = 0.0;
#pragma unroll
                for (int c = 0; c < CD; ++c) {
                    double vn = zn_s[c][lane] * s;    // identical bits to round-5 zn
                    A += vn * vn;
                    dot = fma(vn, cp64[c], dot);
                }
                ed[wv][lane] = (A - 2.0 * dot) + n264[(size_t)q * K + myj];
            }
        }
        __syncthreads();

        // ---- Phase D: wave 0 final pick + loss + writes ----
        if (wv == 0) {
            int bi;
            if (d2 - d1 >= 1e-4f) {
                bi = i1;                      // provably the fp64 argmin
            } else if (d4 - d1 >= 1e-4f) {
                int j1 = i1, j2 = i2, j3 = i3, j4 = i4;
                { int tt; if (j1 > j2) { tt = j1; j1 = j2; j2 = tt; }
                          if (j3 > j4) { tt = j3; j3 = j4; j4 = tt; }
                          if (j1 > j3) { tt = j1; j1 = j3; j3 = tt; }
                          if (j2 > j4) { tt = j2; j2 = j4; j4 = tt; }
                          if (j2 > j3) { tt = j2; j2 = j3; j3 = tt; } }
                double e1 = ed[0][lane], e2 = ed[1][lane];
                double e3 = ed[2][lane], e4 = ed[3][lane];
                double best = e1; bi = j1;
                if (e2 < best) { best = e2; bi = j2; }
                if (e3 < best) { best = e3; bi = j3; }
                if (e4 < best) { best = e4; bi = j4; }
            } else {
                // rare full fp64 rescan (exact round-1 formula; 2-code ILP)
                double zn[CD]; double A = 0.0;
#pragma unroll
                for (int c = 0; c < CD; ++c) {
                    zn[c] = zn_s[c][lane] * s;
                    A += zn[c] * zn[c];
                }
                double best = 1e300; bi = 0;
                const double* cq64 = cbn64 + (size_t)q * K * CD;
                const double* nq64 = n264 + (size_t)q * K;
                for (int k = 0; k < K; k += 2) {
                    double dot0 = 0.0, dot1 = 0.0;
                    const double* c0 = cq64 + (size_t)k * CD;
                    const double* c1 = c0 + CD;
#pragma unroll
                    for (int c = 0; c < CD; ++c) {
                        dot0 = fma(zn[c], c0[c], dot0);
                        dot1 = fma(zn[c], c1[c], dot1);
                    }
                    double dist0 = (A - 2.0 * dot0) + nq64[k];
                    double dist1 = (A - 2.0 * dot1) + nq64[k + 1];
                    if (dist0 < best) { best = dist0; bi = k; }
                    if (dist1 < best) { best = dist1; bi = k + 1; }
                }
            }
            hist_s[q][lane] = bi;

            const float* cr = cb + ((size_t)q * K + bi) * CD;
            double sq = 0.0;
#pragma unroll
            for (int c = 0; c < CD; ++c) {
                double vn = zn_s[c][lane] * s;                    // = round-5 zn bits
                double diff = vn * rnorm - (double)cr[c];         // round-1 loss form
                sq = fma(diff, diff, sq);
            }
#pragma unroll
            for (int off = 32; off > 0; off >>= 1) sq += __shfl_down(sq, off);
            if (lane == 0)
                atomicAdd(&loss[q], (float)(sq * (1.25 / (double)((size_t)B * CD * T))));
            idxi[q * BT + bt] = bi;
            idx_f[(size_t)q * BT + bt] = (float)bi;
        }
        __syncthreads();   // WAR: zn_s/sd/si/ed reused; hist_s visible to Phase A
    }
}

// ---------- k_final as register-blocked fp32 GEMM, T14 stage-split (r12 proven) ----------
#define GT 128
#define GD 128
__global__ __launch_bounds__(256) void k_gemm_final(const float* __restrict__ Wout,
                                                    const float* __restrict__ bo,
                                                    const float* __restrict__ cb,
                                                    const int* __restrict__ idxi,
                                                    float* __restrict__ out) {
    const int t0 = blockIdx.x * GT;
    const int b  = blockIdx.y;
    const int d0 = blockIdx.z * GD;
    const int tx = threadIdx.x & 15;
    const int ty = threadIdx.x >> 4;
    __shared__ float Wt[CD][GD + 4];
    __shared__ float Zt[CD][GT + 4];
    __shared__ float bsum[GD];

    if (threadIdx.x < GD) {
        float sjb = 0.0f;
#pragma unroll
        for (int j = 0; j < Q; ++j) sjb += bo[j * D + d0 + threadIdx.x];
        bsum[threadIdx.x] = sjb;
    }

    float acc[8][8];
#pragma unroll
    for (int r = 0; r < 8; ++r)
#pragma unroll
        for (int cc = 0; cc < 8; ++cc) acc[r][cc] = 0.0f;

    for (int j = 0; j < Q; ++j) {
        // prefetch staging data into registers (no LDS touch -> safe pre-barrier)
        float4 wv[4], zv[4];
#pragma unroll
        for (int r = 0; r < 4; ++r) {
            int i4 = threadIdx.x + r * 256;            // float4 idx, 0..1023
            wv[r] = ((const float4*)(Wout + ((size_t)j * D + d0) * CD))[i4];
            int rowi = i4 >> 3;                        // 0..127
            int kj = idxi[j * BT + (size_t)b * T + t0 + rowi];
            zv[r] = ((const float4*)(cb + ((size_t)j * K + kj) * CD))[i4 & 7];
        }
        __syncthreads();   // WAR: previous iter's reads of Wt/Zt done
#pragma unroll
        for (int r = 0; r < 4; ++r) {
            int i4 = threadIdx.x + r * 256;
            int rowi = i4 >> 3;
            int cq = (i4 & 7) * 4;
            Wt[cq][rowi] = wv[r].x; Wt[cq + 1][rowi] = wv[r].y;
            Wt[cq + 2][rowi] = wv[r].z; Wt[cq + 3][rowi] = wv[r].w;
            Zt[cq][rowi] = zv[r].x; Zt[cq + 1][rowi] = zv[r].y;
            Zt[cq + 2][rowi] = zv[r].z; Zt[cq + 3][rowi] = zv[r].w;
        }
        __syncthreads();
#pragma unroll
        for (int k = 0; k < CD; ++k) {
            float a[8], zb[8];
            *(float4*)&a[0]  = *(const float4*)&Wt[k][ty * 8];
            *(float4*)&a[4]  = *(const float4*)&Wt[k][ty * 8 + 4];
            *(float4*)&zb[0] = *(const float4*)&Zt[k][tx * 8];
            *(float4*)&zb[4] = *(const float4*)&Zt[k][tx * 8 + 4];
#pragma unroll
            for (int r = 0; r < 8; ++r)
#pragma unroll
                for (int cc = 0; cc < 8; ++cc)
                    acc[r][cc] = fmaf(a[r], zb[cc], acc[r][cc]);
        }
    }
#pragma unroll
    for (int r = 0; r < 8; ++r) {
        const int d = d0 + ty * 8 + r;
        const float bias = bsum[ty * 8 + r];
        float4 v0, v1;
        v0.x = acc[r][0] + bias; v0.y = acc[r][1] + bias;
        v0.z = acc[r][2] + bias; v0.w = acc[r][3] + bias;
        v1.x = acc[r][4] + bias; v1.y = acc[r][5] + bias;
        v1.z = acc[r][6] + bias; v1.w = acc[r][7] + bias;
        float* op = out + ((size_t)b * D + d) * T + t0 + tx * 8;
        *(float4*)op = v0;
        *(float4*)(op + 4) = v1;
    }
}

extern "C" void kernel_launch(void* const* d_in, const int* in_sizes, int n_in,
                              void* d_out, int out_size, void* d_ws, size_t ws_size,
                              hipStream_t stream) {
    const float* x     = (const float*)d_in[0];
    const float* Win   = (const float*)d_in[1];
    const float* b_in  = (const float*)d_in[2];
    const float* Wout  = (const float*)d_in[3];
    const float* b_out = (const float*)d_in[4];
    const float* cb    = (const float*)d_in[5];

    float* out0  = (float*)d_out;
    float* idx_f = out0 + (size_t)B * D * T;
    float* loss  = idx_f + (size_t)Q * BT;

    char* sc = (char*)d_out;   // scratch: dead before k_gemm_final writes out0
    double* z0    = (double*)(sc + OFF_Z0);
    double* Mt    = (double*)(sc + OFF_MT);
    double* cbn64 = (double*)(sc + OFF_CBN);
    double* n264  = (double*)(sc + OFF_N264);
    double* Ntab  = (double*)(sc + OFF_NT);
    double* beff  = (double*)(sc + OFF_BEFF);
    float*  cbn32 = (float*)(sc + OFF_C32);
    float*  n232  = (float*)(sc + OFF_N232);
    double* Win64 = (double*)(sc + OFF_W64);
    int*    idxi  = (int*)d_ws;                  // 1 MB, safe for gemm_final

    k_zero_losses<<<1, 64, 0, stream>>>(loss);
    k_norm<<<(Q * K) / 256, 256, 0, stream>>>(cb, cbn64, n264, cbn32, n232);
    k_cvtW<<<(Q * CD * D) / 256, 256, 0, stream>>>(Win, Win64);
    k_prep_N<<<64, 256, 0, stream>>>(Win, Wout, Ntab);
    k_prep_M<<<dim3(K / 256, 8, 8), 256, 0, stream>>>(cb, Ntab, Mt);
    k_prep_beff<<<dim3(CD, Q), 256, 0, stream>>>(Win, b_in, b_out, beff);

    k_gemmZ<<<Q * B * (T / 256), 256, 0, stream>>>(x, Win64, beff, z0);

    k_argmin_fused<<<dim3(T / AT, B), 512, 0, stream>>>(z0, Mt, cbn64, n264,
                                                        cbn32, n232, cb,
                                                        idxi, idx_f, loss);

    k_gemm_final<<<dim3(T / GT, B, D / GD), 256, 0, stream>>>(Wout, b_out, cb, idxi, out0);
}